// Round 1
// baseline (1392.135 us; speedup 1.0000x reference)
//
#include <hip/hip_runtime.h>

#define NB 4
#define NC 64
#define NCR 16
#define NSP 4096

// workspace layout (floats)
#define OFF_T0 0
#define OFF_X1 1048576
#define OFF_Q  2097152
#define OFF_K  2359296
#define OFF_V  2621440
#define OFF_Y  3670016
#define OFF_AC 4718592
#define OFF_ST 4734976

// ---------------- conv3d 3x3x3 SAME + bias ----------------
__global__ __launch_bounds__(256) void conv3d_k(const float* __restrict__ x,
    const float* __restrict__ w, const float* __restrict__ bias, float* __restrict__ out) {
  int blk = blockIdx.x;
  int co = blk & 63, d = (blk >> 6) & 15, b = blk >> 10;
  int h = threadIdx.x >> 4, wp = threadIdx.x & 15;
  float acc = bias[co];
  const float* wco = w + co * (64 * 27);
  const float* xb  = x + b * (64 * 4096);
  int z0 = (d > 0) ? 0 : 1;
  int z1 = (d < 15) ? 3 : 2;
  for (int ci = 0; ci < 64; ++ci) {
    const float* xc = xb + ci * 4096;
    const float* wc = wco + ci * 27;
    for (int dz = z0; dz < z1; ++dz) {
      const float* xz = xc + (d + dz - 1) * 256;
      const float* wz = wc + dz * 9;
      #pragma unroll
      for (int dy = 0; dy < 3; ++dy) {
        int yy = h + dy - 1;
        if (yy < 0 || yy > 15) continue;
        const float* xy = xz + yy * 16;
        #pragma unroll
        for (int dx = 0; dx < 3; ++dx) {
          int xx = wp + dx - 1;
          float xv = (xx >= 0 && xx < 16) ? xy[xx] : 0.f;
          acc = fmaf(wz[dy * 3 + dx], xv, acc);
        }
      }
    }
  }
  out[(b * 64 + co) * 4096 + d * 256 + threadIdx.x] = acc;
}

// ---------------- groupnorm stats: mean + rstd per (b, group) ----------------
__global__ __launch_bounds__(256) void gn_stats_k(const float* __restrict__ t, float* __restrict__ st) {
  int bg = blockIdx.x;                 // b*4+g
  const float* base = t + bg * 65536;  // 16 ch * 4096
  float s = 0.f, ss = 0.f;
  for (int i = threadIdx.x; i < 65536; i += 256) {
    float v = base[i];
    s += v; ss = fmaf(v, v, ss);
  }
  __shared__ float sh[512];
  sh[threadIdx.x] = s; sh[256 + threadIdx.x] = ss;
  __syncthreads();
  for (int stp = 128; stp > 0; stp >>= 1) {
    if (threadIdx.x < stp) {
      sh[threadIdx.x] += sh[threadIdx.x + stp];
      sh[256 + threadIdx.x] += sh[256 + threadIdx.x + stp];
    }
    __syncthreads();
  }
  if (threadIdx.x == 0) {
    float m = sh[0] * (1.f / 65536.f);
    float var = sh[256] * (1.f / 65536.f) - m * m;
    st[bg * 2] = m;
    st[bg * 2 + 1] = rsqrtf(var + 1e-5f);
  }
}

// ---------------- groupnorm apply + relu ----------------
__global__ __launch_bounds__(256) void gn_apply_k(const float* __restrict__ t, const float* __restrict__ st,
    const float* __restrict__ gamma, const float* __restrict__ beta, float* __restrict__ out) {
  int idx = blockIdx.x * 256 + threadIdx.x;
  int c = (idx >> 12) & 63, b = idx >> 18;
  int bg = b * 4 + (c >> 4);
  float m = st[bg * 2], r = st[bg * 2 + 1];
  float v = (t[idx] - m) * r * gamma[c] + beta[c];
  out[idx] = fmaxf(v, 0.f);
}

// ---------------- 1x1 projection: out[b,o,n] = sum_c w[o,c] x[b,c,n] + bias[o] ----------------
template <int OC>
__global__ __launch_bounds__(256) void proj_k(const float* __restrict__ x1, const float* __restrict__ w,
    const float* __restrict__ bias, float* __restrict__ out) {
  int idx = blockIdx.x * 256 + threadIdx.x;
  int o = (idx >> 12) & (OC - 1);
  int b = idx >> (OC == 16 ? 16 : 18);
  int n = idx & 4095;
  const float* xb = x1 + b * 262144 + n;
  const float* wr = w + o * 64;
  float acc = bias[o];
  #pragma unroll
  for (int c = 0; c < 64; ++c) acc = fmaf(wr[c], xb[c << 12], acc);
  out[idx] = acc;
}

// ---------------- flash spatial attention (fp32) ----------------
__global__ __launch_bounds__(256) void flash_k(const float* __restrict__ q, const float* __restrict__ k,
    const float* __restrict__ v, float* __restrict__ sa) {
  __shared__ float qs[16][64];
  __shared__ float ks[16][64];
  __shared__ float vs[64][68];
  __shared__ float ps[64][68];
  __shared__ float red[64][17];
  int b = blockIdx.x >> 6;
  int m0 = (blockIdx.x & 63) * 64;
  int tid = threadIdx.x;
  int tm = tid & 15, tc = tid >> 4;   // 16 m-quads x 16 c/n-quads

  for (int i = tid; i < 1024; i += 256) {
    int qd = i >> 6, m = i & 63;
    qs[qd][m] = q[(b * 16 + qd) * 4096 + m0 + m];
  }
  float acc[4][4] = {};
  float M[4], S[4];
  #pragma unroll
  for (int i = 0; i < 4; ++i) { M[i] = -1e30f; S[i] = 0.f; }

  for (int n0 = 0; n0 < 4096; n0 += 64) {
    for (int i = tid; i < 1024; i += 256) {
      int qd = i >> 6, j = i & 63;
      ks[qd][j] = k[(b * 16 + qd) * 4096 + n0 + j];
    }
    for (int i = tid; i < 4096; i += 256) {
      int c = i >> 6, j = i & 63;
      vs[c][j] = v[(b * 64 + c) * 4096 + n0 + j];
    }
    __syncthreads();

    // scores for this thread's 4m x 4n
    float sc[4][4] = {};
    #pragma unroll
    for (int qd = 0; qd < 16; ++qd) {
      float qv[4], kv[4];
      #pragma unroll
      for (int i = 0; i < 4; ++i) { qv[i] = qs[qd][tm * 4 + i]; kv[i] = ks[qd][tc * 4 + i]; }
      #pragma unroll
      for (int mi = 0; mi < 4; ++mi)
        #pragma unroll
        for (int ni = 0; ni < 4; ++ni) sc[mi][ni] = fmaf(qv[mi], kv[ni], sc[mi][ni]);
    }
    // partial row max
    #pragma unroll
    for (int mi = 0; mi < 4; ++mi) {
      float pm = fmaxf(fmaxf(sc[mi][0], sc[mi][1]), fmaxf(sc[mi][2], sc[mi][3]));
      red[tm * 4 + mi][tc] = pm;
    }
    __syncthreads();
    float scale[4];
    #pragma unroll
    for (int mi = 0; mi < 4; ++mi) {
      int m = tm * 4 + mi;
      float rm = red[m][0];
      #pragma unroll
      for (int j = 1; j < 16; ++j) rm = fmaxf(rm, red[m][j]);
      float Mn = fmaxf(M[mi], rm);
      scale[mi] = __expf(M[mi] - Mn);
      M[mi] = Mn;
    }
    __syncthreads();  // all red reads done before overwrite
    // exp in regs, write p tile + partial row sums
    #pragma unroll
    for (int mi = 0; mi < 4; ++mi) {
      float rs = 0.f;
      #pragma unroll
      for (int ni = 0; ni < 4; ++ni) {
        float p = __expf(sc[mi][ni] - M[mi]);
        rs += p;
        ps[tm * 4 + mi][tc * 4 + ni] = p;
      }
      red[tm * 4 + mi][tc] = rs;
    }
    __syncthreads();
    #pragma unroll
    for (int mi = 0; mi < 4; ++mi) {
      int m = tm * 4 + mi;
      float rs = 0.f;
      #pragma unroll
      for (int j = 0; j < 16; ++j) rs += red[m][j];
      S[mi] = S[mi] * scale[mi] + rs;
      #pragma unroll
      for (int ci = 0; ci < 4; ++ci) acc[mi][ci] *= scale[mi];
    }
    // PV: acc[mi][ci] += sum_n p[m][n] * v[c][n]
    for (int ng = 0; ng < 16; ++ng) {
      int nj = (ng + tm) & 15;  // bank swizzle
      float4 vv[4];
      #pragma unroll
      for (int ci = 0; ci < 4; ++ci)
        vv[ci] = *reinterpret_cast<const float4*>(&vs[tc * 4 + ci][nj * 4]);
      #pragma unroll
      for (int mi = 0; mi < 4; ++mi) {
        float4 pp = *reinterpret_cast<const float4*>(&ps[tm * 4 + mi][nj * 4]);
        #pragma unroll
        for (int ci = 0; ci < 4; ++ci) {
          acc[mi][ci] = fmaf(pp.x, vv[ci].x, acc[mi][ci]);
          acc[mi][ci] = fmaf(pp.y, vv[ci].y, acc[mi][ci]);
          acc[mi][ci] = fmaf(pp.z, vv[ci].z, acc[mi][ci]);
          acc[mi][ci] = fmaf(pp.w, vv[ci].w, acc[mi][ci]);
        }
      }
    }
    __syncthreads();
  }
  #pragma unroll
  for (int mi = 0; mi < 4; ++mi) {
    float inv = 1.f / S[mi];
    #pragma unroll
    for (int ci = 0; ci < 4; ++ci)
      sa[(b * 64 + tc * 4 + ci) * 4096 + m0 + tm * 4 + mi] = acc[mi][ci] * inv;
  }
}

// ---------------- channel attention: gram row + softmax ----------------
__global__ __launch_bounds__(256) void chattn_gram_k(const float* __restrict__ x1, float* __restrict__ Ac) {
  int b = blockIdx.x >> 6, c = blockIdx.x & 63;
  __shared__ float xc[4096];
  __shared__ float grow[64];
  for (int i = threadIdx.x; i < 4096; i += 256) xc[i] = x1[(b * 64 + c) * 4096 + i];
  __syncthreads();
  int ln = threadIdx.x & 63, dg = threadIdx.x >> 6;  // wave id = dg
  #pragma unroll 1
  for (int dd = 0; dd < 16; ++dd) {
    int d = dg * 16 + dd;
    const float* xd = x1 + (b * 64 + d) * 4096;
    float a = 0.f;
    for (int i = 0; i < 64; ++i) {
      int n = i * 64 + ln;
      a = fmaf(xc[n], xd[n], a);
    }
    for (int off = 32; off > 0; off >>= 1) a += __shfl_xor(a, off);
    if (ln == 0) grow[d] = a;
  }
  __syncthreads();
  if (threadIdx.x < 64) {
    float g = grow[threadIdx.x];
    float mx = g;
    for (int off = 32; off > 0; off >>= 1) mx = fmaxf(mx, __shfl_xor(mx, off));
    float e = __expf(g - mx);
    float s = e;
    for (int off = 32; off > 0; off >>= 1) s += __shfl_xor(s, off);
    Ac[(b * 64 + c) * 64 + threadIdx.x] = e / s;
  }
}

// ---------------- y = x1 + sa(in y) + Ac @ x1 ----------------
__global__ __launch_bounds__(256) void ca_apply_k(const float* __restrict__ x1, const float* __restrict__ Ac,
    float* __restrict__ y) {
  int idx = blockIdx.x * 256 + threadIdx.x;
  int n = idx & 4095, c = (idx >> 12) & 63, b = idx >> 18;
  const float* xb = x1 + b * 262144 + n;
  const float* ar = Ac + (b * 64 + c) * 64;
  float acc = x1[idx] + y[idx];
  #pragma unroll
  for (int d = 0; d < 64; ++d) acc = fmaf(ar[d], xb[d << 12], acc);
  y[idx] = acc;
}

extern "C" void kernel_launch(void* const* d_in, const int* in_sizes, int n_in,
                              void* d_out, int out_size, void* d_ws, size_t ws_size,
                              hipStream_t stream) {
  const float* x       = (const float*)d_in[0];
  const float* w_i     = (const float*)d_in[1];
  const float* b_i     = (const float*)d_in[2];
  const float* gamma_i = (const float*)d_in[3];
  const float* beta_i  = (const float*)d_in[4];
  const float* w_q     = (const float*)d_in[5];
  const float* b_q     = (const float*)d_in[6];
  const float* w_k     = (const float*)d_in[7];
  const float* b_k     = (const float*)d_in[8];
  const float* w_v     = (const float*)d_in[9];
  const float* b_v     = (const float*)d_in[10];
  const float* w_o     = (const float*)d_in[11];
  const float* b_o     = (const float*)d_in[12];
  const float* gamma_o = (const float*)d_in[13];
  const float* beta_o  = (const float*)d_in[14];
  float* ws = (float*)d_ws;
  float* t0 = ws + OFF_T0;
  float* x1 = ws + OFF_X1;
  float* qb = ws + OFF_Q;
  float* kb = ws + OFF_K;
  float* vb = ws + OFF_V;
  float* yb = ws + OFF_Y;
  float* ac = ws + OFF_AC;
  float* st = ws + OFF_ST;
  float* outp = (float*)d_out;

  conv3d_k<<<4096, 256, 0, stream>>>(x, w_i, b_i, t0);
  gn_stats_k<<<16, 256, 0, stream>>>(t0, st);
  gn_apply_k<<<4096, 256, 0, stream>>>(t0, st, gamma_i, beta_i, x1);

  proj_k<16><<<1024, 256, 0, stream>>>(x1, w_q, b_q, qb);
  proj_k<16><<<1024, 256, 0, stream>>>(x1, w_k, b_k, kb);
  proj_k<64><<<4096, 256, 0, stream>>>(x1, w_v, b_v, vb);

  flash_k<<<256, 256, 0, stream>>>(qb, kb, vb, yb);          // yb = sa
  chattn_gram_k<<<256, 256, 0, stream>>>(x1, ac);
  ca_apply_k<<<4096, 256, 0, stream>>>(x1, ac, yb);          // yb = x1 + sa + ca

  conv3d_k<<<4096, 256, 0, stream>>>(yb, w_o, b_o, t0);
  gn_stats_k<<<16, 256, 0, stream>>>(t0, st);
  gn_apply_k<<<4096, 256, 0, stream>>>(t0, st, gamma_o, beta_o, outp);
}

// Round 2
// 1095.799 us; speedup vs baseline: 1.2704x; 1.2704x over previous
//
#include <hip/hip_runtime.h>

#define NB 4
#define NC 64
#define NSP 4096

// workspace layout (float offsets)
#define OFF_T0 0
#define OFF_X1 1048576
#define OFF_QT 2097152   // bf16 [4][4096][32]  (1 MB)
#define OFF_KT 2359296   // bf16 [4][4096][32]  (1 MB)
#define OFF_VB 2621440   // bf16 [4][64][4096]  (2 MB)
#define OFF_Y  3145728
#define OFF_AC 4194304
#define OFF_ST 4210688

typedef __attribute__((ext_vector_type(8))) short short8v;
typedef __attribute__((ext_vector_type(4))) short short4v;
typedef __attribute__((ext_vector_type(4))) float f32x4;

__device__ __forceinline__ ushort f2bf(float f) {
  union { float f; unsigned u; } v; v.f = f;
  unsigned r = (v.u + 0x7fffu + ((v.u >> 16) & 1u)) >> 16;
  return (ushort)r;
}

// ---------------- conv3d 3x3x3 SAME + bias ----------------
__global__ __launch_bounds__(256) void conv3d_k(const float* __restrict__ x,
    const float* __restrict__ w, const float* __restrict__ bias, float* __restrict__ out) {
  int blk = blockIdx.x;
  int co = blk & 63, d = (blk >> 6) & 15, b = blk >> 10;
  int h = threadIdx.x >> 4, wp = threadIdx.x & 15;
  float acc = bias[co];
  const float* wco = w + co * (64 * 27);
  const float* xb  = x + b * (64 * 4096);
  int z0 = (d > 0) ? 0 : 1;
  int z1 = (d < 15) ? 3 : 2;
  for (int ci = 0; ci < 64; ++ci) {
    const float* xc = xb + ci * 4096;
    const float* wc = wco + ci * 27;
    for (int dz = z0; dz < z1; ++dz) {
      const float* xz = xc + (d + dz - 1) * 256;
      const float* wz = wc + dz * 9;
      #pragma unroll
      for (int dy = 0; dy < 3; ++dy) {
        int yy = h + dy - 1;
        if (yy < 0 || yy > 15) continue;
        const float* xy = xz + yy * 16;
        #pragma unroll
        for (int dx = 0; dx < 3; ++dx) {
          int xx = wp + dx - 1;
          float xv = (xx >= 0 && xx < 16) ? xy[xx] : 0.f;
          acc = fmaf(wz[dy * 3 + dx], xv, acc);
        }
      }
    }
  }
  out[(b * 64 + co) * 4096 + d * 256 + threadIdx.x] = acc;
}

// ---------------- groupnorm stats ----------------
__global__ __launch_bounds__(256) void gn_stats_k(const float* __restrict__ t, float* __restrict__ st) {
  int bg = blockIdx.x;
  const float* base = t + bg * 65536;
  float s = 0.f, ss = 0.f;
  for (int i = threadIdx.x; i < 65536; i += 256) {
    float v = base[i];
    s += v; ss = fmaf(v, v, ss);
  }
  __shared__ float sh[512];
  sh[threadIdx.x] = s; sh[256 + threadIdx.x] = ss;
  __syncthreads();
  for (int stp = 128; stp > 0; stp >>= 1) {
    if (threadIdx.x < stp) {
      sh[threadIdx.x] += sh[threadIdx.x + stp];
      sh[256 + threadIdx.x] += sh[256 + threadIdx.x + stp];
    }
    __syncthreads();
  }
  if (threadIdx.x == 0) {
    float m = sh[0] * (1.f / 65536.f);
    float var = sh[256] * (1.f / 65536.f) - m * m;
    st[bg * 2] = m;
    st[bg * 2 + 1] = rsqrtf(var + 1e-5f);
  }
}

// ---------------- groupnorm apply + relu ----------------
__global__ __launch_bounds__(256) void gn_apply_k(const float* __restrict__ t, const float* __restrict__ st,
    const float* __restrict__ gamma, const float* __restrict__ beta, float* __restrict__ out) {
  int idx = blockIdx.x * 256 + threadIdx.x;
  int c = (idx >> 12) & 63, b = idx >> 18;
  int bg = b * 4 + (c >> 4);
  float m = st[bg * 2], r = st[bg * 2 + 1];
  float v = (t[idx] - m) * r * gamma[c] + beta[c];
  out[idx] = fmaxf(v, 0.f);
}

// ---------------- q/k projection -> bf16 [b][n][32], d padded with zeros ----------------
__global__ __launch_bounds__(256) void proj_qk_k(const float* __restrict__ x1, const float* __restrict__ w,
    const float* __restrict__ bias, ushort* __restrict__ out) {
  int idx = blockIdx.x * 256 + threadIdx.x;   // 4*16*4096
  int o = (idx >> 12) & 15, b = idx >> 16, n = idx & 4095;
  const float* xb = x1 + b * 262144 + n;
  const float* wr = w + o * 64;
  float acc = bias[o];
  #pragma unroll
  for (int c = 0; c < 64; ++c) acc = fmaf(wr[c], xb[c << 12], acc);
  out[(size_t)(b * 4096 + n) * 32 + o] = f2bf(acc);
  out[(size_t)(b * 4096 + n) * 32 + 16 + o] = 0;
}

// ---------------- v projection -> bf16 [b][c][n] ----------------
__global__ __launch_bounds__(256) void proj_v_k(const float* __restrict__ x1, const float* __restrict__ w,
    const float* __restrict__ bias, ushort* __restrict__ out) {
  int idx = blockIdx.x * 256 + threadIdx.x;   // 4*64*4096
  int o = (idx >> 12) & 63, b = idx >> 18, n = idx & 4095;
  const float* xb = x1 + b * 262144 + n;
  const float* wr = w + o * 64;
  float acc = bias[o];
  #pragma unroll
  for (int c = 0; c < 64; ++c) acc = fmaf(wr[c], xb[c << 12], acc);
  out[idx] = f2bf(acc);
}

// ---------------- flash spatial attention, bf16 MFMA ----------------
#define KP 40
#define VP 72
__global__ __launch_bounds__(256) void flash_mfma_k(const ushort* __restrict__ qt,
    const ushort* __restrict__ kt, const ushort* __restrict__ vb, float* __restrict__ sa) {
  __shared__ __align__(16) ushort kls[64 * KP];
  __shared__ __align__(16) ushort vls[64 * VP];
  __shared__ __align__(16) ushort pls[64 * VP];
  int b = blockIdx.x >> 6;
  int m0 = (blockIdx.x & 63) * 64;
  int tid = threadIdx.x;
  int w = tid >> 6, l = tid & 63;
  int lm = l & 15, lg = l >> 4;

  // per-wave Q B-fragment: B[k=d][col=m], lane holds Q[(lg*8+j)][m0+w*16+lm]
  short8v qf = *reinterpret_cast<const short8v*>(
      qt + (size_t)(b * 4096 + m0 + w * 16 + lm) * 32 + lg * 8);

  f32x4 acc[4] = {};
  float M = -1e30f, S = 0.f;

  const ushort* ktb = kt + (size_t)b * 4096 * 32;
  const ushort* vbb = vb + (size_t)b * 64 * 4096;
  int sr = tid >> 2, sq = tid & 3;

  for (int n0 = 0; n0 < 4096; n0 += 64) {
    __syncthreads();
    // stage K tile: 64 n-rows x 32 d (upper 16 are zeros from global)
    *reinterpret_cast<short8v*>(&kls[sr * KP + sq * 8]) =
        *reinterpret_cast<const short8v*>(ktb + (size_t)(n0 + sr) * 32 + sq * 8);
    // stage V tile: 64 c-rows x 64 n
    {
      const ushort* vsrc = vbb + (size_t)sr * 4096 + n0 + sq * 16;
      *reinterpret_cast<short8v*>(&vls[sr * VP + sq * 16]) =
          *reinterpret_cast<const short8v*>(vsrc);
      *reinterpret_cast<short8v*>(&vls[sr * VP + sq * 16 + 8]) =
          *reinterpret_cast<const short8v*>(vsrc + 8);
    }
    __syncthreads();

    // QK^T: S[n][m], 4 n-subtiles of 16
    f32x4 sf[4];
    #pragma unroll
    for (int nt = 0; nt < 4; ++nt) {
      short8v kf = *reinterpret_cast<const short8v*>(&kls[(nt * 16 + lm) * KP + lg * 8]);
      f32x4 z = {};
      sf[nt] = __builtin_amdgcn_mfma_f32_16x16x32_bf16(kf, qf, z, 0, 0, 0);
    }
    // online softmax over n; lane's column m is fixed
    float tmax = -1e30f;
    #pragma unroll
    for (int nt = 0; nt < 4; ++nt)
      #pragma unroll
      for (int r = 0; r < 4; ++r) tmax = fmaxf(tmax, sf[nt][r]);
    tmax = fmaxf(tmax, __shfl_xor(tmax, 16));
    tmax = fmaxf(tmax, __shfl_xor(tmax, 32));
    float Mn = fmaxf(M, tmax);
    float scale = __expf(M - Mn);
    M = Mn;
    float tsum = 0.f;
    ushort pb[16];
    #pragma unroll
    for (int nt = 0; nt < 4; ++nt)
      #pragma unroll
      for (int r = 0; r < 4; ++r) {
        float p = __expf(sf[nt][r] - Mn);
        tsum += p;
        pb[nt * 4 + r] = f2bf(p);
      }
    tsum += __shfl_xor(tsum, 16);
    tsum += __shfl_xor(tsum, 32);
    S = S * scale + tsum;
    #pragma unroll
    for (int ct = 0; ct < 4; ++ct)
      #pragma unroll
      for (int r = 0; r < 4; ++r) acc[ct][r] *= scale;
    // write P (bf16) to wave-private rows of pls: [m][n], n = nt*16 + lg*4 + r
    #pragma unroll
    for (int nt = 0; nt < 4; ++nt) {
      short4v pv;
      pv[0] = (short)pb[nt * 4 + 0]; pv[1] = (short)pb[nt * 4 + 1];
      pv[2] = (short)pb[nt * 4 + 2]; pv[3] = (short)pb[nt * 4 + 3];
      *reinterpret_cast<short4v*>(&pls[(w * 16 + lm) * VP + nt * 16 + lg * 4]) = pv;
    }
    asm volatile("s_waitcnt lgkmcnt(0)" ::: "memory");
    // PV: acc[c][m] += V[c][n] * P[n][m]
    #pragma unroll
    for (int nh = 0; nh < 2; ++nh) {
      short8v pf = *reinterpret_cast<const short8v*>(&pls[(w * 16 + lm) * VP + nh * 32 + lg * 8]);
      #pragma unroll
      for (int ct = 0; ct < 4; ++ct) {
        short8v vf = *reinterpret_cast<const short8v*>(&vls[(ct * 16 + lm) * VP + nh * 32 + lg * 8]);
        acc[ct] = __builtin_amdgcn_mfma_f32_16x16x32_bf16(vf, pf, acc[ct], 0, 0, 0);
      }
    }
  }
  float inv = 1.f / S;
  #pragma unroll
  for (int ct = 0; ct < 4; ++ct)
    #pragma unroll
    for (int r = 0; r < 4; ++r)
      sa[(size_t)(b * 64 + ct * 16 + lg * 4 + r) * 4096 + m0 + w * 16 + lm] = acc[ct][r] * inv;
}

// ---------------- channel attention: gram row + softmax ----------------
__global__ __launch_bounds__(256) void chattn_gram_k(const float* __restrict__ x1, float* __restrict__ Ac) {
  int b = blockIdx.x >> 6, c = blockIdx.x & 63;
  __shared__ float xc[4096];
  __shared__ float grow[64];
  for (int i = threadIdx.x; i < 4096; i += 256) xc[i] = x1[(b * 64 + c) * 4096 + i];
  __syncthreads();
  int ln = threadIdx.x & 63, dg = threadIdx.x >> 6;
  #pragma unroll 1
  for (int dd = 0; dd < 16; ++dd) {
    int d = dg * 16 + dd;
    const float* xd = x1 + (b * 64 + d) * 4096;
    float a = 0.f;
    for (int i = 0; i < 64; ++i) {
      int n = i * 64 + ln;
      a = fmaf(xc[n], xd[n], a);
    }
    for (int off = 32; off > 0; off >>= 1) a += __shfl_xor(a, off);
    if (ln == 0) grow[d] = a;
  }
  __syncthreads();
  if (threadIdx.x < 64) {
    float g = grow[threadIdx.x];
    float mx = g;
    for (int off = 32; off > 0; off >>= 1) mx = fmaxf(mx, __shfl_xor(mx, off));
    float e = __expf(g - mx);
    float s = e;
    for (int off = 32; off > 0; off >>= 1) s += __shfl_xor(s, off);
    Ac[(b * 64 + c) * 64 + threadIdx.x] = e / s;
  }
}

// ---------------- y = x1 + sa(in y) + Ac @ x1 ----------------
__global__ __launch_bounds__(256) void ca_apply_k(const float* __restrict__ x1, const float* __restrict__ Ac,
    float* __restrict__ y) {
  int idx = blockIdx.x * 256 + threadIdx.x;
  int n = idx & 4095, c = (idx >> 12) & 63, b = idx >> 18;
  const float* xb = x1 + b * 262144 + n;
  const float* ar = Ac + (b * 64 + c) * 64;
  float acc = x1[idx] + y[idx];
  #pragma unroll
  for (int d = 0; d < 64; ++d) acc = fmaf(ar[d], xb[d << 12], acc);
  y[idx] = acc;
}

extern "C" void kernel_launch(void* const* d_in, const int* in_sizes, int n_in,
                              void* d_out, int out_size, void* d_ws, size_t ws_size,
                              hipStream_t stream) {
  const float* x       = (const float*)d_in[0];
  const float* w_i     = (const float*)d_in[1];
  const float* b_i     = (const float*)d_in[2];
  const float* gamma_i = (const float*)d_in[3];
  const float* beta_i  = (const float*)d_in[4];
  const float* w_q     = (const float*)d_in[5];
  const float* b_q     = (const float*)d_in[6];
  const float* w_k     = (const float*)d_in[7];
  const float* b_k     = (const float*)d_in[8];
  const float* w_v     = (const float*)d_in[9];
  const float* b_v     = (const float*)d_in[10];
  const float* w_o     = (const float*)d_in[11];
  const float* b_o     = (const float*)d_in[12];
  const float* gamma_o = (const float*)d_in[13];
  const float* beta_o  = (const float*)d_in[14];
  float* ws = (float*)d_ws;
  float* t0 = ws + OFF_T0;
  float* x1 = ws + OFF_X1;
  ushort* qt = (ushort*)(ws + OFF_QT);
  ushort* kt = (ushort*)(ws + OFF_KT);
  ushort* vbp = (ushort*)(ws + OFF_VB);
  float* yb = ws + OFF_Y;
  float* ac = ws + OFF_AC;
  float* st = ws + OFF_ST;
  float* outp = (float*)d_out;

  conv3d_k<<<4096, 256, 0, stream>>>(x, w_i, b_i, t0);
  gn_stats_k<<<16, 256, 0, stream>>>(t0, st);
  gn_apply_k<<<4096, 256, 0, stream>>>(t0, st, gamma_i, beta_i, x1);

  proj_qk_k<<<1024, 256, 0, stream>>>(x1, w_q, b_q, qt);
  proj_qk_k<<<1024, 256, 0, stream>>>(x1, w_k, b_k, kt);
  proj_v_k<<<4096, 256, 0, stream>>>(x1, w_v, b_v, vbp);

  flash_mfma_k<<<256, 256, 0, stream>>>(qt, kt, vbp, yb);
  chattn_gram_k<<<256, 256, 0, stream>>>(x1, ac);
  ca_apply_k<<<4096, 256, 0, stream>>>(x1, ac, yb);

  conv3d_k<<<4096, 256, 0, stream>>>(yb, w_o, b_o, t0);
  gn_stats_k<<<16, 256, 0, stream>>>(t0, st);
  gn_apply_k<<<4096, 256, 0, stream>>>(t0, st, gamma_o, beta_o, outp);
}

// Round 3
// 440.890 us; speedup vs baseline: 3.1576x; 2.4854x over previous
//
#include <hip/hip_runtime.h>

// workspace layout (float offsets); yb (flash out) aliases t0
#define OFF_T0  0
#define OFF_X1  1048576
#define OFF_QT  2097152
#define OFF_KT  2359296
#define OFF_VB  2621440
#define OFF_YT  3145728
#define OFF_XB  3670016
#define OFF_AC  4194304
#define OFF_WBI 4210688
#define OFF_WBO 4265984
#define OFF_PT  4321280
#define OFF_ST  4321792

typedef __attribute__((ext_vector_type(8))) short short8v;
typedef __attribute__((ext_vector_type(4))) short short4v;
typedef __attribute__((ext_vector_type(4))) float f32x4;

__device__ __forceinline__ ushort f2bf(float f) {
  union { float f; unsigned u; } v; v.f = f;
  unsigned r = (v.u + 0x7fffu + ((v.u >> 16) & 1u)) >> 16;
  return (ushort)r;
}

// ---------------- weight reorder: [co][ci][27] f32 -> [co][tap][ci] bf16 ----------------
__global__ __launch_bounds__(256) void wcvt_k(const float* __restrict__ w, ushort* __restrict__ wb) {
  int idx = blockIdx.x * 256 + threadIdx.x;   // 64*27*64 = 110592
  int ci = idx & 63, tap = (idx >> 6) % 27, co = idx / (64 * 27);
  wb[idx] = f2bf(w[(co * 64 + ci) * 27 + tap]);
}

// ---------------- x convert: [b][ci][dhw] f32 -> [b][dhw][ci] bf16 ----------------
__global__ __launch_bounds__(256) void xcvt_k(const float* __restrict__ x, ushort* __restrict__ xb) {
  int idx = blockIdx.x * 256 + threadIdx.x;   // 4*4096*64
  int ci = idx & 63;
  int rest = idx >> 6;
  int n = rest & 4095, b = rest >> 12;
  xb[idx] = f2bf(x[(size_t)(b * 64 + ci) * 4096 + n]);
}

// ---------------- conv3d as implicit GEMM, bf16 MFMA ----------------
// grid: b(4) x d0(16) x hq(4) = 256 blocks, 256 threads (4 waves 2x2)
__global__ __launch_bounds__(256) void conv_mfma_k(const ushort* __restrict__ xt,
    const ushort* __restrict__ wb, const float* __restrict__ bias, float* __restrict__ out) {
  __shared__ __align__(16) ushort xls[18 * 18 * 64];  // [dz*6+h_s][w_s][ci]
  int blk = blockIdx.x;
  int h0 = (blk & 3) * 4;
  int d0 = (blk >> 2) & 15;
  int b  = blk >> 6;
  int tid = threadIdx.x;

  // ---- stage haloed tile, w pre-shifted (+1), per-chunk XOR swizzle ----
  const ushort* xtb = xt + (size_t)b * 4096 * 64;
  for (int u = tid; u < 324; u += 256) {
    int w_s = u % 18;
    int row = u / 18;            // dz*6 + h_s
    int dz = row / 6, h_s = row - dz * 6;
    int d = d0 + dz - 1, h = h0 + h_s - 1, w = w_s - 1;
    ushort* dst = &xls[(row * 18 + w_s) * 64];
    int swz = w_s & 7;
    if (d >= 0 && d < 16 && h >= 0 && h < 16 && w >= 0 && w < 16) {
      const ushort* src = xtb + (size_t)(d * 256 + h * 16 + w) * 64;
      #pragma unroll
      for (int c = 0; c < 8; ++c)
        *reinterpret_cast<short8v*>(dst + ((c ^ swz) << 3)) =
            *reinterpret_cast<const short8v*>(src + (c << 3));
    } else {
      short8v z = {};
      #pragma unroll
      for (int c = 0; c < 8; ++c)
        *reinterpret_cast<short8v*>(dst + ((c ^ swz) << 3)) = z;
    }
  }
  __syncthreads();

  int wv = tid >> 6, l = tid & 63;
  int wn = wv >> 1, wc = wv & 1;
  int lm = l & 15, lg = l >> 4;

  f32x4 acc[2][2] = {};
  const ushort* wbase0 = wb + (size_t)((wc * 2 + 0) * 16 + lm) * 1728 + lg * 8;
  const ushort* wbase1 = wb + (size_t)((wc * 2 + 1) * 16 + lm) * 1728 + lg * 8;

  #pragma unroll 6
  for (int s = 0; s < 54; ++s) {
    int tap = s >> 1, c0h = s & 1;
    int dz = tap / 9, dyx = tap - dz * 9;
    int dy = dyx / 3, dx = dyx - dy * 3;
    int wrow = lm + dx;
    int chunk = ((c0h * 4 + lg) ^ (wrow & 7)) << 3;
    int r0 = ((dz * 6 + wn * 2 + dy) * 18 + wrow) * 64 + chunk;
    short8v a0 = *reinterpret_cast<const short8v*>(&xls[r0]);
    short8v a1 = *reinterpret_cast<const short8v*>(&xls[r0 + 18 * 64]);
    short8v b0 = *reinterpret_cast<const short8v*>(wbase0 + s * 32);
    short8v b1 = *reinterpret_cast<const short8v*>(wbase1 + s * 32);
    acc[0][0] = __builtin_amdgcn_mfma_f32_16x16x32_bf16(a0, b0, acc[0][0], 0, 0, 0);
    acc[0][1] = __builtin_amdgcn_mfma_f32_16x16x32_bf16(a0, b1, acc[0][1], 0, 0, 0);
    acc[1][0] = __builtin_amdgcn_mfma_f32_16x16x32_bf16(a1, b0, acc[1][0], 0, 0, 0);
    acc[1][1] = __builtin_amdgcn_mfma_f32_16x16x32_bf16(a1, b1, acc[1][1], 0, 0, 0);
  }

  #pragma unroll
  for (int j = 0; j < 2; ++j) {
    int co = (wc * 2 + j) * 16 + lm;
    float bs = bias[co];
    #pragma unroll
    for (int i = 0; i < 2; ++i) {
      int hh = h0 + wn * 2 + i;
      float4 o;
      o.x = acc[i][j][0] + bs; o.y = acc[i][j][1] + bs;
      o.z = acc[i][j][2] + bs; o.w = acc[i][j][3] + bs;
      *reinterpret_cast<float4*>(&out[(size_t)(b * 64 + co) * 4096 + d0 * 256 + hh * 16 + lg * 4]) = o;
    }
  }
}

// ---------------- groupnorm stats: stage 1 (256 blocks) + stage 2 ----------------
__global__ __launch_bounds__(256) void gn_stats1_k(const float* __restrict__ t, float* __restrict__ pt) {
  int blk = blockIdx.x;   // bg*16 + slice
  const float4* base = reinterpret_cast<const float4*>(t + (size_t)blk * 4096);
  float s = 0.f, ss = 0.f;
  for (int i = threadIdx.x; i < 1024; i += 256) {
    float4 v = base[i];
    s += v.x + v.y + v.z + v.w;
    ss = fmaf(v.x, v.x, ss); ss = fmaf(v.y, v.y, ss);
    ss = fmaf(v.z, v.z, ss); ss = fmaf(v.w, v.w, ss);
  }
  __shared__ float sh[512];
  sh[threadIdx.x] = s; sh[256 + threadIdx.x] = ss;
  __syncthreads();
  for (int stp = 128; stp > 0; stp >>= 1) {
    if (threadIdx.x < stp) {
      sh[threadIdx.x] += sh[threadIdx.x + stp];
      sh[256 + threadIdx.x] += sh[256 + threadIdx.x + stp];
    }
    __syncthreads();
  }
  if (threadIdx.x == 0) { pt[blk * 2] = sh[0]; pt[blk * 2 + 1] = sh[256]; }
}

__global__ __launch_bounds__(64) void gn_stats2_k(const float* __restrict__ pt, float* __restrict__ st) {
  int t = threadIdx.x;
  if (t < 16) {
    float s = 0.f, ss = 0.f;
    for (int i = 0; i < 16; ++i) { s += pt[(t * 16 + i) * 2]; ss += pt[(t * 16 + i) * 2 + 1]; }
    float m = s * (1.f / 65536.f);
    float var = ss * (1.f / 65536.f) - m * m;
    st[t * 2] = m;
    st[t * 2 + 1] = rsqrtf(var + 1e-5f);
  }
}

// ---------------- groupnorm apply + relu ----------------
__global__ __launch_bounds__(256) void gn_apply_k(const float* __restrict__ t, const float* __restrict__ st,
    const float* __restrict__ gamma, const float* __restrict__ beta, float* __restrict__ out) {
  int idx = blockIdx.x * 256 + threadIdx.x;
  int c = (idx >> 12) & 63, b = idx >> 18;
  int bg = b * 4 + (c >> 4);
  float m = st[bg * 2], r = st[bg * 2 + 1];
  float v = (t[idx] - m) * r * gamma[c] + beta[c];
  out[idx] = fmaxf(v, 0.f);
}

// ---------------- q/k projection -> bf16 [b][n][32], d padded with zeros ----------------
__global__ __launch_bounds__(256) void proj_qk_k(const float* __restrict__ x1, const float* __restrict__ w,
    const float* __restrict__ bias, ushort* __restrict__ out) {
  int idx = blockIdx.x * 256 + threadIdx.x;
  int o = (idx >> 12) & 15, b = idx >> 16, n = idx & 4095;
  const float* xb = x1 + b * 262144 + n;
  const float* wr = w + o * 64;
  float acc = bias[o];
  #pragma unroll
  for (int c = 0; c < 64; ++c) acc = fmaf(wr[c], xb[c << 12], acc);
  out[(size_t)(b * 4096 + n) * 32 + o] = f2bf(acc);
  out[(size_t)(b * 4096 + n) * 32 + 16 + o] = 0;
}

// ---------------- v projection -> bf16 [b][c][n] ----------------
__global__ __launch_bounds__(256) void proj_v_k(const float* __restrict__ x1, const float* __restrict__ w,
    const float* __restrict__ bias, ushort* __restrict__ out) {
  int idx = blockIdx.x * 256 + threadIdx.x;
  int o = (idx >> 12) & 63, b = idx >> 18, n = idx & 4095;
  const float* xb = x1 + b * 262144 + n;
  const float* wr = w + o * 64;
  float acc = bias[o];
  #pragma unroll
  for (int c = 0; c < 64; ++c) acc = fmaf(wr[c], xb[c << 12], acc);
  out[idx] = f2bf(acc);
}

// ---------------- flash spatial attention, bf16 MFMA ----------------
#define KP 40
#define VP 72
__global__ __launch_bounds__(256) void flash_mfma_k(const ushort* __restrict__ qt,
    const ushort* __restrict__ kt, const ushort* __restrict__ vb, float* __restrict__ sa) {
  __shared__ __align__(16) ushort kls[64 * KP];
  __shared__ __align__(16) ushort vls[64 * VP];
  __shared__ __align__(16) ushort pls[64 * VP];
  int b = blockIdx.x >> 6;
  int m0 = (blockIdx.x & 63) * 64;
  int tid = threadIdx.x;
  int w = tid >> 6, l = tid & 63;
  int lm = l & 15, lg = l >> 4;

  short8v qf = *reinterpret_cast<const short8v*>(
      qt + (size_t)(b * 4096 + m0 + w * 16 + lm) * 32 + lg * 8);

  f32x4 acc[4] = {};
  float M = -1e30f, S = 0.f;

  const ushort* ktb = kt + (size_t)b * 4096 * 32;
  const ushort* vbb = vb + (size_t)b * 64 * 4096;
  int sr = tid >> 2, sq = tid & 3;

  for (int n0 = 0; n0 < 4096; n0 += 64) {
    __syncthreads();
    *reinterpret_cast<short8v*>(&kls[sr * KP + sq * 8]) =
        *reinterpret_cast<const short8v*>(ktb + (size_t)(n0 + sr) * 32 + sq * 8);
    {
      const ushort* vsrc = vbb + (size_t)sr * 4096 + n0 + sq * 16;
      *reinterpret_cast<short8v*>(&vls[sr * VP + sq * 16]) =
          *reinterpret_cast<const short8v*>(vsrc);
      *reinterpret_cast<short8v*>(&vls[sr * VP + sq * 16 + 8]) =
          *reinterpret_cast<const short8v*>(vsrc + 8);
    }
    __syncthreads();

    f32x4 sf[4];
    #pragma unroll
    for (int nt = 0; nt < 4; ++nt) {
      short8v kf = *reinterpret_cast<const short8v*>(&kls[(nt * 16 + lm) * KP + lg * 8]);
      f32x4 z = {};
      sf[nt] = __builtin_amdgcn_mfma_f32_16x16x32_bf16(kf, qf, z, 0, 0, 0);
    }
    float tmax = -1e30f;
    #pragma unroll
    for (int nt = 0; nt < 4; ++nt)
      #pragma unroll
      for (int r = 0; r < 4; ++r) tmax = fmaxf(tmax, sf[nt][r]);
    tmax = fmaxf(tmax, __shfl_xor(tmax, 16));
    tmax = fmaxf(tmax, __shfl_xor(tmax, 32));
    float Mn = fmaxf(M, tmax);
    float scale = __expf(M - Mn);
    M = Mn;
    float tsum = 0.f;
    ushort pb[16];
    #pragma unroll
    for (int nt = 0; nt < 4; ++nt)
      #pragma unroll
      for (int r = 0; r < 4; ++r) {
        float p = __expf(sf[nt][r] - Mn);
        tsum += p;
        pb[nt * 4 + r] = f2bf(p);
      }
    tsum += __shfl_xor(tsum, 16);
    tsum += __shfl_xor(tsum, 32);
    S = S * scale + tsum;
    #pragma unroll
    for (int ct = 0; ct < 4; ++ct)
      #pragma unroll
      for (int r = 0; r < 4; ++r) acc[ct][r] *= scale;
    #pragma unroll
    for (int nt = 0; nt < 4; ++nt) {
      short4v pv;
      pv[0] = (short)pb[nt * 4 + 0]; pv[1] = (short)pb[nt * 4 + 1];
      pv[2] = (short)pb[nt * 4 + 2]; pv[3] = (short)pb[nt * 4 + 3];
      *reinterpret_cast<short4v*>(&pls[(w * 16 + lm) * VP + nt * 16 + lg * 4]) = pv;
    }
    asm volatile("s_waitcnt lgkmcnt(0)" ::: "memory");
    __builtin_amdgcn_sched_barrier(0);
    #pragma unroll
    for (int nh = 0; nh < 2; ++nh) {
      short8v pf = *reinterpret_cast<const short8v*>(&pls[(w * 16 + lm) * VP + nh * 32 + lg * 8]);
      #pragma unroll
      for (int ct = 0; ct < 4; ++ct) {
        short8v vf = *reinterpret_cast<const short8v*>(&vls[(ct * 16 + lm) * VP + nh * 32 + lg * 8]);
        acc[ct] = __builtin_amdgcn_mfma_f32_16x16x32_bf16(vf, pf, acc[ct], 0, 0, 0);
      }
    }
  }
  float inv = 1.f / S;
  #pragma unroll
  for (int ct = 0; ct < 4; ++ct)
    #pragma unroll
    for (int r = 0; r < 4; ++r)
      sa[(size_t)(b * 64 + ct * 16 + lg * 4 + r) * 4096 + m0 + w * 16 + lm] = acc[ct][r] * inv;
}

// ---------------- channel attention: gram row + softmax ----------------
__global__ __launch_bounds__(256) void chattn_gram_k(const float* __restrict__ x1, float* __restrict__ Ac) {
  int b = blockIdx.x >> 6, c = blockIdx.x & 63;
  __shared__ float xc[4096];
  __shared__ float grow[64];
  for (int i = threadIdx.x; i < 4096; i += 256) xc[i] = x1[(b * 64 + c) * 4096 + i];
  __syncthreads();
  int ln = threadIdx.x & 63, dg = threadIdx.x >> 6;
  #pragma unroll 1
  for (int dd = 0; dd < 16; ++dd) {
    int d = dg * 16 + dd;
    const float* xd = x1 + (b * 64 + d) * 4096;
    float a = 0.f;
    for (int i = 0; i < 64; ++i) {
      int n = i * 64 + ln;
      a = fmaf(xc[n], xd[n], a);
    }
    for (int off = 32; off > 0; off >>= 1) a += __shfl_xor(a, off);
    if (ln == 0) grow[d] = a;
  }
  __syncthreads();
  if (threadIdx.x < 64) {
    float g = grow[threadIdx.x];
    float mx = g;
    for (int off = 32; off > 0; off >>= 1) mx = fmaxf(mx, __shfl_xor(mx, off));
    float e = __expf(g - mx);
    float s = e;
    for (int off = 32; off > 0; off >>= 1) s += __shfl_xor(s, off);
    Ac[(b * 64 + c) * 64 + threadIdx.x] = e / s;
  }
}

// ---------------- y = x1 + sa + Ac @ x1 -> bf16 transposed [b][n][ci] ----------------
__global__ __launch_bounds__(256) void ca_apply_k(const float* __restrict__ x1, const float* __restrict__ Ac,
    const float* __restrict__ sa, ushort* __restrict__ yt) {
  int idx = blockIdx.x * 256 + threadIdx.x;
  int n = idx & 4095, c = (idx >> 12) & 63, b = idx >> 18;
  const float* xb = x1 + b * 262144 + n;
  const float* ar = Ac + (b * 64 + c) * 64;
  float acc = x1[idx] + sa[idx];
  #pragma unroll
  for (int d = 0; d < 64; ++d) acc = fmaf(ar[d], xb[d << 12], acc);
  yt[(size_t)(b * 4096 + n) * 64 + c] = f2bf(acc);
}

extern "C" void kernel_launch(void* const* d_in, const int* in_sizes, int n_in,
                              void* d_out, int out_size, void* d_ws, size_t ws_size,
                              hipStream_t stream) {
  const float* x       = (const float*)d_in[0];
  const float* w_i     = (const float*)d_in[1];
  const float* b_i     = (const float*)d_in[2];
  const float* gamma_i = (const float*)d_in[3];
  const float* beta_i  = (const float*)d_in[4];
  const float* w_q     = (const float*)d_in[5];
  const float* b_q     = (const float*)d_in[6];
  const float* w_k     = (const float*)d_in[7];
  const float* b_k     = (const float*)d_in[8];
  const float* w_v     = (const float*)d_in[9];
  const float* b_v     = (const float*)d_in[10];
  const float* w_o     = (const float*)d_in[11];
  const float* b_o     = (const float*)d_in[12];
  const float* gamma_o = (const float*)d_in[13];
  const float* beta_o  = (const float*)d_in[14];
  float* ws = (float*)d_ws;
  float* t0 = ws + OFF_T0;
  float* x1 = ws + OFF_X1;
  ushort* qt  = (ushort*)(ws + OFF_QT);
  ushort* kt  = (ushort*)(ws + OFF_KT);
  ushort* vbp = (ushort*)(ws + OFF_VB);
  float* yb = ws + OFF_T0;             // sa aliases t0 (t0 dead between gn_apply_i and conv2)
  ushort* ytp = (ushort*)(ws + OFF_YT);
  ushort* xbp = (ushort*)(ws + OFF_XB);
  float* ac = ws + OFF_AC;
  ushort* wbi = (ushort*)(ws + OFF_WBI);
  ushort* wbo = (ushort*)(ws + OFF_WBO);
  float* pt = ws + OFF_PT;
  float* st = ws + OFF_ST;
  float* outp = (float*)d_out;

  wcvt_k<<<432, 256, 0, stream>>>(w_i, wbi);
  wcvt_k<<<432, 256, 0, stream>>>(w_o, wbo);
  xcvt_k<<<4096, 256, 0, stream>>>(x, xbp);

  conv_mfma_k<<<256, 256, 0, stream>>>(xbp, wbi, b_i, t0);
  gn_stats1_k<<<256, 256, 0, stream>>>(t0, pt);
  gn_stats2_k<<<1, 64, 0, stream>>>(pt, st);
  gn_apply_k<<<4096, 256, 0, stream>>>(t0, st, gamma_i, beta_i, x1);

  proj_qk_k<<<1024, 256, 0, stream>>>(x1, w_q, b_q, qt);
  proj_qk_k<<<1024, 256, 0, stream>>>(x1, w_k, b_k, kt);
  proj_v_k<<<4096, 256, 0, stream>>>(x1, w_v, b_v, vbp);

  flash_mfma_k<<<256, 256, 0, stream>>>(qt, kt, vbp, yb);
  chattn_gram_k<<<256, 256, 0, stream>>>(x1, ac);
  ca_apply_k<<<4096, 256, 0, stream>>>(x1, ac, yb, ytp);

  conv_mfma_k<<<256, 256, 0, stream>>>(ytp, wbo, b_o, t0);
  gn_stats1_k<<<256, 256, 0, stream>>>(t0, pt);
  gn_stats2_k<<<1, 64, 0, stream>>>(pt, st);
  gn_apply_k<<<4096, 256, 0, stream>>>(t0, st, gamma_o, beta_o, outp);
}

// Round 4
// 224.189 us; speedup vs baseline: 6.2096x; 1.9666x over previous
//
#include <hip/hip_runtime.h>

// workspace layout (float offsets); sa aliases t0; gram partials alias qt
#define OFF_T0  0
#define OFF_X1  1048576
#define OFF_QT  2097152
#define OFF_KT  2359296
#define OFF_VB  2621440
#define OFF_YT  3145728
#define OFF_XB  3670016
#define OFF_AC  4194304
#define OFF_WBI 4210688
#define OFF_WBO 4265984
#define OFF_PT  4321280
#define OFF_ST  4321792

typedef __attribute__((ext_vector_type(8))) short short8v;
typedef __attribute__((ext_vector_type(4))) short short4v;
typedef __attribute__((ext_vector_type(4))) float f32x4;

__device__ __forceinline__ ushort f2bf(float f) {
  union { float f; unsigned u; } v; v.f = f;
  unsigned r = (v.u + 0x7fffu + ((v.u >> 16) & 1u)) >> 16;
  return (ushort)r;
}

// ---------------- weight reorder: [co][ci][27] f32 -> [co][tap][ci] bf16 ----------------
__global__ __launch_bounds__(256) void wcvt_k(const float* __restrict__ w, ushort* __restrict__ wb) {
  int idx = blockIdx.x * 256 + threadIdx.x;
  int ci = idx & 63, tap = (idx >> 6) % 27, co = idx / (64 * 27);
  wb[idx] = f2bf(w[(co * 64 + ci) * 27 + tap]);
}

// ---------------- x convert: [b][ci][dhw] f32 -> [b][dhw][ci] bf16, tiled transpose ----------------
__global__ __launch_bounds__(256) void xcvt_k(const float* __restrict__ x, ushort* __restrict__ xb) {
  __shared__ ushort tl[64 * 72];
  int b = blockIdx.x >> 6;
  int n0 = (blockIdx.x & 63) * 64;
  int t = threadIdx.x;
  int ci = t >> 2, q = t & 3;
  const float* src = x + (size_t)(b * 64 + ci) * 4096 + n0 + q * 16;
  #pragma unroll
  for (int i = 0; i < 4; ++i) {
    float4 v = *reinterpret_cast<const float4*>(src + i * 4);
    tl[(q * 16 + i * 4 + 0) * 72 + ci] = f2bf(v.x);
    tl[(q * 16 + i * 4 + 1) * 72 + ci] = f2bf(v.y);
    tl[(q * 16 + i * 4 + 2) * 72 + ci] = f2bf(v.z);
    tl[(q * 16 + i * 4 + 3) * 72 + ci] = f2bf(v.w);
  }
  __syncthreads();
  int n = t >> 2, qq = t & 3;
  ushort* dst = xb + (size_t)(b * 4096 + n0 + n) * 64 + qq * 16;
  *reinterpret_cast<short8v*>(dst) = *reinterpret_cast<const short8v*>(&tl[n * 72 + qq * 16]);
  *reinterpret_cast<short8v*>(dst + 8) = *reinterpret_cast<const short8v*>(&tl[n * 72 + qq * 16 + 8]);
}

// ---------------- conv3d as implicit GEMM, bf16 MFMA ----------------
__global__ __launch_bounds__(256) void conv_mfma_k(const ushort* __restrict__ xt,
    const ushort* __restrict__ wb, const float* __restrict__ bias, float* __restrict__ out) {
  __shared__ __align__(16) ushort xls[18 * 18 * 64];
  int blk = blockIdx.x;
  int h0 = (blk & 3) * 4;
  int d0 = (blk >> 2) & 15;
  int b  = blk >> 6;
  int tid = threadIdx.x;

  const ushort* xtb = xt + (size_t)b * 4096 * 64;
  for (int u = tid; u < 324; u += 256) {
    int w_s = u % 18;
    int row = u / 18;
    int dz = row / 6, h_s = row - dz * 6;
    int d = d0 + dz - 1, h = h0 + h_s - 1, w = w_s - 1;
    ushort* dst = &xls[(row * 18 + w_s) * 64];
    int swz = w_s & 7;
    if (d >= 0 && d < 16 && h >= 0 && h < 16 && w >= 0 && w < 16) {
      const ushort* src = xtb + (size_t)(d * 256 + h * 16 + w) * 64;
      #pragma unroll
      for (int c = 0; c < 8; ++c)
        *reinterpret_cast<short8v*>(dst + ((c ^ swz) << 3)) =
            *reinterpret_cast<const short8v*>(src + (c << 3));
    } else {
      short8v z = {};
      #pragma unroll
      for (int c = 0; c < 8; ++c)
        *reinterpret_cast<short8v*>(dst + ((c ^ swz) << 3)) = z;
    }
  }
  __syncthreads();

  int wv = tid >> 6, l = tid & 63;
  int wn = wv >> 1, wc = wv & 1;
  int lm = l & 15, lg = l >> 4;

  f32x4 acc[2][2] = {};
  const ushort* wbase0 = wb + (size_t)((wc * 2 + 0) * 16 + lm) * 1728 + lg * 8;
  const ushort* wbase1 = wb + (size_t)((wc * 2 + 1) * 16 + lm) * 1728 + lg * 8;

  #pragma unroll 6
  for (int s = 0; s < 54; ++s) {
    int tap = s >> 1, c0h = s & 1;
    int dz = tap / 9, dyx = tap - dz * 9;
    int dy = dyx / 3, dx = dyx - dy * 3;
    int wrow = lm + dx;
    int chunk = ((c0h * 4 + lg) ^ (wrow & 7)) << 3;
    int r0 = ((dz * 6 + wn * 2 + dy) * 18 + wrow) * 64 + chunk;
    short8v a0 = *reinterpret_cast<const short8v*>(&xls[r0]);
    short8v a1 = *reinterpret_cast<const short8v*>(&xls[r0 + 18 * 64]);
    short8v b0 = *reinterpret_cast<const short8v*>(wbase0 + s * 32);
    short8v b1 = *reinterpret_cast<const short8v*>(wbase1 + s * 32);
    acc[0][0] = __builtin_amdgcn_mfma_f32_16x16x32_bf16(a0, b0, acc[0][0], 0, 0, 0);
    acc[0][1] = __builtin_amdgcn_mfma_f32_16x16x32_bf16(a0, b1, acc[0][1], 0, 0, 0);
    acc[1][0] = __builtin_amdgcn_mfma_f32_16x16x32_bf16(a1, b0, acc[1][0], 0, 0, 0);
    acc[1][1] = __builtin_amdgcn_mfma_f32_16x16x32_bf16(a1, b1, acc[1][1], 0, 0, 0);
  }

  #pragma unroll
  for (int j = 0; j < 2; ++j) {
    int co = (wc * 2 + j) * 16 + lm;
    float bs = bias[co];
    #pragma unroll
    for (int i = 0; i < 2; ++i) {
      int hh = h0 + wn * 2 + i;
      float4 o;
      o.x = acc[i][j][0] + bs; o.y = acc[i][j][1] + bs;
      o.z = acc[i][j][2] + bs; o.w = acc[i][j][3] + bs;
      *reinterpret_cast<float4*>(&out[(size_t)(b * 64 + co) * 4096 + d0 * 256 + hh * 16 + lg * 4]) = o;
    }
  }
}

// ---------------- groupnorm stats ----------------
__global__ __launch_bounds__(256) void gn_stats1_k(const float* __restrict__ t, float* __restrict__ pt) {
  int blk = blockIdx.x;
  const float4* base = reinterpret_cast<const float4*>(t + (size_t)blk * 4096);
  float s = 0.f, ss = 0.f;
  for (int i = threadIdx.x; i < 1024; i += 256) {
    float4 v = base[i];
    s += v.x + v.y + v.z + v.w;
    ss = fmaf(v.x, v.x, ss); ss = fmaf(v.y, v.y, ss);
    ss = fmaf(v.z, v.z, ss); ss = fmaf(v.w, v.w, ss);
  }
  __shared__ float sh[512];
  sh[threadIdx.x] = s; sh[256 + threadIdx.x] = ss;
  __syncthreads();
  for (int stp = 128; stp > 0; stp >>= 1) {
    if (threadIdx.x < stp) {
      sh[threadIdx.x] += sh[threadIdx.x + stp];
      sh[256 + threadIdx.x] += sh[256 + threadIdx.x + stp];
    }
    __syncthreads();
  }
  if (threadIdx.x == 0) { pt[blk * 2] = sh[0]; pt[blk * 2 + 1] = sh[256]; }
}

__global__ __launch_bounds__(64) void gn_stats2_k(const float* __restrict__ pt, float* __restrict__ st) {
  int t = threadIdx.x;
  if (t < 16) {
    float s = 0.f, ss = 0.f;
    for (int i = 0; i < 16; ++i) { s += pt[(t * 16 + i) * 2]; ss += pt[(t * 16 + i) * 2 + 1]; }
    float m = s * (1.f / 65536.f);
    float var = ss * (1.f / 65536.f) - m * m;
    st[t * 2] = m;
    st[t * 2 + 1] = rsqrtf(var + 1e-5f);
  }
}

// ---------------- groupnorm apply + relu ----------------
__global__ __launch_bounds__(256) void gn_apply_k(const float* __restrict__ t, const float* __restrict__ st,
    const float* __restrict__ gamma, const float* __restrict__ beta, float* __restrict__ out) {
  int idx = blockIdx.x * 256 + threadIdx.x;
  int c = (idx >> 12) & 63, b = idx >> 18;
  int bg = b * 4 + (c >> 4);
  float m = st[bg * 2], r = st[bg * 2 + 1];
  float v = (t[idx] - m) * r * gamma[c] + beta[c];
  out[idx] = fmaxf(v, 0.f);
}

// ---------------- q/k projection -> bf16 [b][n][32] ----------------
__global__ __launch_bounds__(256) void proj_qk_k(const float* __restrict__ x1, const float* __restrict__ w,
    const float* __restrict__ bias, ushort* __restrict__ out) {
  int idx = blockIdx.x * 256 + threadIdx.x;
  int o = (idx >> 12) & 15, b = idx >> 16, n = idx & 4095;
  const float* xb = x1 + b * 262144 + n;
  const float* wr = w + o * 64;
  float acc = bias[o];
  #pragma unroll
  for (int c = 0; c < 64; ++c) acc = fmaf(wr[c], xb[c << 12], acc);
  out[(size_t)(b * 4096 + n) * 32 + o] = f2bf(acc);
  out[(size_t)(b * 4096 + n) * 32 + 16 + o] = 0;
}

// ---------------- v projection -> bf16 [b][c][n] ----------------
__global__ __launch_bounds__(256) void proj_v_k(const float* __restrict__ x1, const float* __restrict__ w,
    const float* __restrict__ bias, ushort* __restrict__ out) {
  int idx = blockIdx.x * 256 + threadIdx.x;
  int o = (idx >> 12) & 63, b = idx >> 18, n = idx & 4095;
  const float* xb = x1 + b * 262144 + n;
  const float* wr = w + o * 64;
  float acc = bias[o];
  #pragma unroll
  for (int c = 0; c < 64; ++c) acc = fmaf(wr[c], xb[c << 12], acc);
  out[idx] = f2bf(acc);
}

// ---------------- flash spatial attention, bf16 MFMA ----------------
#define KP 40
#define VP 72
__global__ __launch_bounds__(256) void flash_mfma_k(const ushort* __restrict__ qt,
    const ushort* __restrict__ kt, const ushort* __restrict__ vb, float* __restrict__ sa) {
  __shared__ __align__(16) ushort kls[64 * KP];
  __shared__ __align__(16) ushort vls[64 * VP];
  __shared__ __align__(16) ushort pls[64 * VP];
  int b = blockIdx.x >> 6;
  int m0 = (blockIdx.x & 63) * 64;
  int tid = threadIdx.x;
  int w = tid >> 6, l = tid & 63;
  int lm = l & 15, lg = l >> 4;

  short8v qf = *reinterpret_cast<const short8v*>(
      qt + (size_t)(b * 4096 + m0 + w * 16 + lm) * 32 + lg * 8);

  f32x4 acc[4] = {};
  float M = -1e30f, S = 0.f;

  const ushort* ktb = kt + (size_t)b * 4096 * 32;
  const ushort* vbb = vb + (size_t)b * 64 * 4096;
  int sr = tid >> 2, sq = tid & 3;

  for (int n0 = 0; n0 < 4096; n0 += 64) {
    __syncthreads();
    *reinterpret_cast<short8v*>(&kls[sr * KP + sq * 8]) =
        *reinterpret_cast<const short8v*>(ktb + (size_t)(n0 + sr) * 32 + sq * 8);
    {
      const ushort* vsrc = vbb + (size_t)sr * 4096 + n0 + sq * 16;
      *reinterpret_cast<short8v*>(&vls[sr * VP + sq * 16]) =
          *reinterpret_cast<const short8v*>(vsrc);
      *reinterpret_cast<short8v*>(&vls[sr * VP + sq * 16 + 8]) =
          *reinterpret_cast<const short8v*>(vsrc + 8);
    }
    __syncthreads();

    f32x4 sf[4];
    #pragma unroll
    for (int nt = 0; nt < 4; ++nt) {
      short8v kf = *reinterpret_cast<const short8v*>(&kls[(nt * 16 + lm) * KP + lg * 8]);
      f32x4 z = {};
      sf[nt] = __builtin_amdgcn_mfma_f32_16x16x32_bf16(kf, qf, z, 0, 0, 0);
    }
    float tmax = -1e30f;
    #pragma unroll
    for (int nt = 0; nt < 4; ++nt)
      #pragma unroll
      for (int r = 0; r < 4; ++r) tmax = fmaxf(tmax, sf[nt][r]);
    tmax = fmaxf(tmax, __shfl_xor(tmax, 16));
    tmax = fmaxf(tmax, __shfl_xor(tmax, 32));
    float Mn = fmaxf(M, tmax);
    float scale = __expf(M - Mn);
    M = Mn;
    float tsum = 0.f;
    ushort pb[16];
    #pragma unroll
    for (int nt = 0; nt < 4; ++nt)
      #pragma unroll
      for (int r = 0; r < 4; ++r) {
        float p = __expf(sf[nt][r] - Mn);
        tsum += p;
        pb[nt * 4 + r] = f2bf(p);
      }
    tsum += __shfl_xor(tsum, 16);
    tsum += __shfl_xor(tsum, 32);
    S = S * scale + tsum;
    #pragma unroll
    for (int ct = 0; ct < 4; ++ct)
      #pragma unroll
      for (int r = 0; r < 4; ++r) acc[ct][r] *= scale;
    #pragma unroll
    for (int nt = 0; nt < 4; ++nt) {
      short4v pv;
      pv[0] = (short)pb[nt * 4 + 0]; pv[1] = (short)pb[nt * 4 + 1];
      pv[2] = (short)pb[nt * 4 + 2]; pv[3] = (short)pb[nt * 4 + 3];
      *reinterpret_cast<short4v*>(&pls[(w * 16 + lm) * VP + nt * 16 + lg * 4]) = pv;
    }
    asm volatile("s_waitcnt lgkmcnt(0)" ::: "memory");
    __builtin_amdgcn_sched_barrier(0);
    #pragma unroll
    for (int nh = 0; nh < 2; ++nh) {
      short8v pf = *reinterpret_cast<const short8v*>(&pls[(w * 16 + lm) * VP + nh * 32 + lg * 8]);
      #pragma unroll
      for (int ct = 0; ct < 4; ++ct) {
        short8v vf = *reinterpret_cast<const short8v*>(&vls[(ct * 16 + lm) * VP + nh * 32 + lg * 8]);
        acc[ct] = __builtin_amdgcn_mfma_f32_16x16x32_bf16(vf, pf, acc[ct], 0, 0, 0);
      }
    }
  }
  float inv = 1.f / S;
  #pragma unroll
  for (int ct = 0; ct < 4; ++ct)
    #pragma unroll
    for (int r = 0; r < 4; ++r)
      sa[(size_t)(b * 64 + ct * 16 + lg * 4 + r) * 4096 + m0 + w * 16 + lm] = acc[ct][r] * inv;
}

// ---------------- channel gram partials: pg[b*8+ks][c][d] over K=512 slice, hi/lo bf16 MFMA ----------------
__global__ __launch_bounds__(256) void gram_partial_k(const float* __restrict__ x1, float* __restrict__ pg) {
  __shared__ __align__(16) ushort hi[64 * 64];
  __shared__ __align__(16) ushort lo[64 * 64];
  int b = blockIdx.x >> 3, ks = blockIdx.x & 7;
  int tid = threadIdx.x;
  int wv = tid >> 6, l = tid & 63, lm = l & 15, lg = l >> 4;
  int wr = wv >> 1, wd = wv & 1;
  f32x4 acc[2][2] = {};
  int sr = tid >> 2, sq = tid & 3;
  const float* xb = x1 + (size_t)b * 262144;

  for (int kt = 0; kt < 8; ++kt) {
    int n0 = ks * 512 + kt * 64;
    __syncthreads();
    const float* src = xb + (size_t)sr * 4096 + n0 + sq * 16;
    #pragma unroll
    for (int c2 = 0; c2 < 2; ++c2) {
      int chunk = sq * 2 + c2;
      int dchunk = chunk ^ (sr & 7);
      short8v hvv, lvv;
      #pragma unroll
      for (int j = 0; j < 8; ++j) {
        float v = src[c2 * 8 + j];
        ushort hb = f2bf(v);
        union { float f; unsigned u; } uu; uu.u = ((unsigned)hb) << 16;
        hvv[j] = (short)hb;
        lvv[j] = (short)f2bf(v - uu.f);
      }
      *reinterpret_cast<short8v*>(&hi[sr * 64 + dchunk * 8]) = hvv;
      *reinterpret_cast<short8v*>(&lo[sr * 64 + dchunk * 8]) = lvv;
    }
    __syncthreads();
    #pragma unroll
    for (int kk = 0; kk < 2; ++kk) {
      short8v ah[2], al[2], bh[2], bl[2];
      #pragma unroll
      for (int i = 0; i < 2; ++i) {
        int rc = wr * 32 + i * 16 + lm;
        int ca = ((kk * 4 + lg) ^ (rc & 7)) * 8;
        ah[i] = *reinterpret_cast<const short8v*>(&hi[rc * 64 + ca]);
        al[i] = *reinterpret_cast<const short8v*>(&lo[rc * 64 + ca]);
        int rd = wd * 32 + i * 16 + lm;
        int cb = ((kk * 4 + lg) ^ (rd & 7)) * 8;
        bh[i] = *reinterpret_cast<const short8v*>(&hi[rd * 64 + cb]);
        bl[i] = *reinterpret_cast<const short8v*>(&lo[rd * 64 + cb]);
      }
      #pragma unroll
      for (int i = 0; i < 2; ++i)
        #pragma unroll
        for (int j = 0; j < 2; ++j) {
          acc[i][j] = __builtin_amdgcn_mfma_f32_16x16x32_bf16(ah[i], bh[j], acc[i][j], 0, 0, 0);
          acc[i][j] = __builtin_amdgcn_mfma_f32_16x16x32_bf16(ah[i], bl[j], acc[i][j], 0, 0, 0);
          acc[i][j] = __builtin_amdgcn_mfma_f32_16x16x32_bf16(al[i], bh[j], acc[i][j], 0, 0, 0);
        }
    }
  }
  float* pgb = pg + (size_t)blockIdx.x * 4096;
  #pragma unroll
  for (int i = 0; i < 2; ++i)
    #pragma unroll
    for (int j = 0; j < 2; ++j)
      #pragma unroll
      for (int r = 0; r < 4; ++r) {
        int c = wr * 32 + i * 16 + lg * 4 + r;
        int d = wd * 32 + j * 16 + lm;
        pgb[c * 64 + d] = acc[i][j][r];
      }
}

// ---------------- reduce partials + row softmax -> Ac[b][c][d] ----------------
__global__ __launch_bounds__(256) void gram_softmax_k(const float* __restrict__ pg, float* __restrict__ Ac) {
  int b = blockIdx.x;
  int t = threadIdx.x;
  int r = t >> 2, q = t & 3;
  float4 s[4] = {};
  for (int ks = 0; ks < 8; ++ks) {
    const float* row = pg + ((size_t)(b * 8 + ks) * 64 + r) * 64 + q * 16;
    #pragma unroll
    for (int i = 0; i < 4; ++i) {
      float4 v = *reinterpret_cast<const float4*>(row + i * 4);
      s[i].x += v.x; s[i].y += v.y; s[i].z += v.z; s[i].w += v.w;
    }
  }
  float mx = -1e30f;
  #pragma unroll
  for (int i = 0; i < 4; ++i)
    mx = fmaxf(mx, fmaxf(fmaxf(s[i].x, s[i].y), fmaxf(s[i].z, s[i].w)));
  mx = fmaxf(mx, __shfl_xor(mx, 1));
  mx = fmaxf(mx, __shfl_xor(mx, 2));
  float sum = 0.f;
  #pragma unroll
  for (int i = 0; i < 4; ++i) {
    s[i].x = __expf(s[i].x - mx); s[i].y = __expf(s[i].y - mx);
    s[i].z = __expf(s[i].z - mx); s[i].w = __expf(s[i].w - mx);
    sum += s[i].x + s[i].y + s[i].z + s[i].w;
  }
  sum += __shfl_xor(sum, 1);
  sum += __shfl_xor(sum, 2);
  float inv = 1.f / sum;
  float* dst = Ac + ((size_t)(b * 64 + r)) * 64 + q * 16;
  #pragma unroll
  for (int i = 0; i < 4; ++i) {
    float4 o; o.x = s[i].x * inv; o.y = s[i].y * inv; o.z = s[i].z * inv; o.w = s[i].w * inv;
    *reinterpret_cast<float4*>(dst + i * 4) = o;
  }
}

// ---------------- y = x1 + sa + Ac @ x1 -> bf16 transposed [b][n][ci] ----------------
__global__ __launch_bounds__(256) void ca_apply_k(const float* __restrict__ x1, const float* __restrict__ Ac,
    const float* __restrict__ sa, ushort* __restrict__ yt) {
  int idx = blockIdx.x * 256 + threadIdx.x;
  int n = idx & 4095, c = (idx >> 12) & 63, b = idx >> 18;
  const float* xb = x1 + b * 262144 + n;
  const float* ar = Ac + (b * 64 + c) * 64;
  float acc = x1[idx] + sa[idx];
  #pragma unroll
  for (int d = 0; d < 64; ++d) acc = fmaf(ar[d], xb[d << 12], acc);
  yt[(size_t)(b * 4096 + n) * 64 + c] = f2bf(acc);
}

extern "C" void kernel_launch(void* const* d_in, const int* in_sizes, int n_in,
                              void* d_out, int out_size, void* d_ws, size_t ws_size,
                              hipStream_t stream) {
  const float* x       = (const float*)d_in[0];
  const float* w_i     = (const float*)d_in[1];
  const float* b_i     = (const float*)d_in[2];
  const float* gamma_i = (const float*)d_in[3];
  const float* beta_i  = (const float*)d_in[4];
  const float* w_q     = (const float*)d_in[5];
  const float* b_q     = (const float*)d_in[6];
  const float* w_k     = (const float*)d_in[7];
  const float* b_k     = (const float*)d_in[8];
  const float* w_v     = (const float*)d_in[9];
  const float* b_v     = (const float*)d_in[10];
  const float* w_o     = (const float*)d_in[11];
  const float* b_o     = (const float*)d_in[12];
  const float* gamma_o = (const float*)d_in[13];
  const float* beta_o  = (const float*)d_in[14];
  float* ws = (float*)d_ws;
  float* t0 = ws + OFF_T0;
  float* x1 = ws + OFF_X1;
  ushort* qt  = (ushort*)(ws + OFF_QT);
  ushort* kt  = (ushort*)(ws + OFF_KT);
  ushort* vbp = (ushort*)(ws + OFF_VB);
  float* yb = ws + OFF_T0;             // sa aliases t0
  float* pg = ws + OFF_QT;             // gram partials alias qt (dead after flash)
  ushort* ytp = (ushort*)(ws + OFF_YT);
  ushort* xbp = (ushort*)(ws + OFF_XB);
  float* ac = ws + OFF_AC;
  ushort* wbi = (ushort*)(ws + OFF_WBI);
  ushort* wbo = (ushort*)(ws + OFF_WBO);
  float* pt = ws + OFF_PT;
  float* st = ws + OFF_ST;
  float* outp = (float*)d_out;

  wcvt_k<<<432, 256, 0, stream>>>(w_i, wbi);
  wcvt_k<<<432, 256, 0, stream>>>(w_o, wbo);
  xcvt_k<<<256, 256, 0, stream>>>(x, xbp);

  conv_mfma_k<<<256, 256, 0, stream>>>(xbp, wbi, b_i, t0);
  gn_stats1_k<<<256, 256, 0, stream>>>(t0, pt);
  gn_stats2_k<<<1, 64, 0, stream>>>(pt, st);
  gn_apply_k<<<4096, 256, 0, stream>>>(t0, st, gamma_i, beta_i, x1);

  proj_qk_k<<<1024, 256, 0, stream>>>(x1, w_q, b_q, qt);
  proj_qk_k<<<1024, 256, 0, stream>>>(x1, w_k, b_k, kt);
  proj_v_k<<<4096, 256, 0, stream>>>(x1, w_v, b_v, vbp);

  flash_mfma_k<<<256, 256, 0, stream>>>(qt, kt, vbp, yb);

  gram_partial_k<<<32, 256, 0, stream>>>(x1, pg);
  gram_softmax_k<<<4, 256, 0, stream>>>(pg, ac);
  ca_apply_k<<<4096, 256, 0, stream>>>(x1, ac, yb, ytp);

  conv_mfma_k<<<256, 256, 0, stream>>>(ytp, wbo, b_o, t0);
  gn_stats1_k<<<256, 256, 0, stream>>>(t0, pt);
  gn_stats2_k<<<1, 64, 0, stream>>>(pt, st);
  gn_apply_k<<<4096, 256, 0, stream>>>(t0, st, gamma_o, beta_o, outp);
}

// Round 5
// 185.310 us; speedup vs baseline: 7.5125x; 1.2098x over previous
//
#include <hip/hip_runtime.h>

// workspace layout (float offsets); sa aliases t0; gram partials alias qt
#define OFF_T0  0
#define OFF_X1  1048576
#define OFF_QT  2097152
#define OFF_KT  2359296
#define OFF_VB  2621440
#define OFF_YT  3145728
#define OFF_XB  3670016
#define OFF_AC  4194304
#define OFF_WBI 4210688
#define OFF_WBO 4265984
#define OFF_PT  4321280
#define OFF_ST  4321792

typedef __attribute__((ext_vector_type(8))) short short8v;
typedef __attribute__((ext_vector_type(4))) short short4v;
typedef __attribute__((ext_vector_type(4))) float f32x4;

__device__ __forceinline__ ushort f2bf(float f) {
  union { float f; unsigned u; } v; v.f = f;
  unsigned r = (v.u + 0x7fffu + ((v.u >> 16) & 1u)) >> 16;
  return (ushort)r;
}

// ---------------- weight reorder: [co][ci][27] f32 -> [co][tap][ci] bf16 ----------------
__global__ __launch_bounds__(256) void wcvt_k(const float* __restrict__ w, ushort* __restrict__ wb) {
  int idx = blockIdx.x * 256 + threadIdx.x;
  int ci = idx & 63, tap = (idx >> 6) % 27, co = idx / (64 * 27);
  wb[idx] = f2bf(w[(co * 64 + ci) * 27 + tap]);
}

// ---------------- x convert: [b][ci][dhw] f32 -> [b][dhw][ci] bf16, tiled transpose ----------------
__global__ __launch_bounds__(256) void xcvt_k(const float* __restrict__ x, ushort* __restrict__ xb) {
  __shared__ ushort tl[64 * 72];
  int b = blockIdx.x >> 6;
  int n0 = (blockIdx.x & 63) * 64;
  int t = threadIdx.x;
  int ci = t >> 2, q = t & 3;
  const float* src = x + (size_t)(b * 64 + ci) * 4096 + n0 + q * 16;
  #pragma unroll
  for (int i = 0; i < 4; ++i) {
    float4 v = *reinterpret_cast<const float4*>(src + i * 4);
    tl[(q * 16 + i * 4 + 0) * 72 + ci] = f2bf(v.x);
    tl[(q * 16 + i * 4 + 1) * 72 + ci] = f2bf(v.y);
    tl[(q * 16 + i * 4 + 2) * 72 + ci] = f2bf(v.z);
    tl[(q * 16 + i * 4 + 3) * 72 + ci] = f2bf(v.w);
  }
  __syncthreads();
  int n = t >> 2, qq = t & 3;
  ushort* dst = xb + (size_t)(b * 4096 + n0 + n) * 64 + qq * 16;
  *reinterpret_cast<short8v*>(dst) = *reinterpret_cast<const short8v*>(&tl[n * 72 + qq * 16]);
  *reinterpret_cast<short8v*>(dst + 8) = *reinterpret_cast<const short8v*>(&tl[n * 72 + qq * 16 + 8]);
}

// ---------------- conv3d as implicit GEMM, bf16 MFMA ----------------
__global__ __launch_bounds__(256) void conv_mfma_k(const ushort* __restrict__ xt,
    const ushort* __restrict__ wb, const float* __restrict__ bias, float* __restrict__ out) {
  __shared__ __align__(16) ushort xls[18 * 18 * 64];
  int blk = blockIdx.x;
  int h0 = (blk & 3) * 4;
  int d0 = (blk >> 2) & 15;
  int b  = blk >> 6;
  int tid = threadIdx.x;

  const ushort* xtb = xt + (size_t)b * 4096 * 64;
  for (int u = tid; u < 324; u += 256) {
    int w_s = u % 18;
    int row = u / 18;
    int dz = row / 6, h_s = row - dz * 6;
    int d = d0 + dz - 1, h = h0 + h_s - 1, w = w_s - 1;
    ushort* dst = &xls[(row * 18 + w_s) * 64];
    int swz = w_s & 7;
    if (d >= 0 && d < 16 && h >= 0 && h < 16 && w >= 0 && w < 16) {
      const ushort* src = xtb + (size_t)(d * 256 + h * 16 + w) * 64;
      #pragma unroll
      for (int c = 0; c < 8; ++c)
        *reinterpret_cast<short8v*>(dst + ((c ^ swz) << 3)) =
            *reinterpret_cast<const short8v*>(src + (c << 3));
    } else {
      short8v z = {};
      #pragma unroll
      for (int c = 0; c < 8; ++c)
        *reinterpret_cast<short8v*>(dst + ((c ^ swz) << 3)) = z;
    }
  }
  __syncthreads();

  int wv = tid >> 6, l = tid & 63;
  int wn = wv >> 1, wc = wv & 1;
  int lm = l & 15, lg = l >> 4;

  f32x4 acc[2][2] = {};
  const ushort* wbase0 = wb + (size_t)((wc * 2 + 0) * 16 + lm) * 1728 + lg * 8;
  const ushort* wbase1 = wb + (size_t)((wc * 2 + 1) * 16 + lm) * 1728 + lg * 8;

  #pragma unroll 6
  for (int s = 0; s < 54; ++s) {
    int tap = s >> 1, c0h = s & 1;
    int dz = tap / 9, dyx = tap - dz * 9;
    int dy = dyx / 3, dx = dyx - dy * 3;
    int wrow = lm + dx;
    int chunk = ((c0h * 4 + lg) ^ (wrow & 7)) << 3;
    int r0 = ((dz * 6 + wn * 2 + dy) * 18 + wrow) * 64 + chunk;
    short8v a0 = *reinterpret_cast<const short8v*>(&xls[r0]);
    short8v a1 = *reinterpret_cast<const short8v*>(&xls[r0 + 18 * 64]);
    short8v b0 = *reinterpret_cast<const short8v*>(wbase0 + s * 32);
    short8v b1 = *reinterpret_cast<const short8v*>(wbase1 + s * 32);
    acc[0][0] = __builtin_amdgcn_mfma_f32_16x16x32_bf16(a0, b0, acc[0][0], 0, 0, 0);
    acc[0][1] = __builtin_amdgcn_mfma_f32_16x16x32_bf16(a0, b1, acc[0][1], 0, 0, 0);
    acc[1][0] = __builtin_amdgcn_mfma_f32_16x16x32_bf16(a1, b0, acc[1][0], 0, 0, 0);
    acc[1][1] = __builtin_amdgcn_mfma_f32_16x16x32_bf16(a1, b1, acc[1][1], 0, 0, 0);
  }

  #pragma unroll
  for (int j = 0; j < 2; ++j) {
    int co = (wc * 2 + j) * 16 + lm;
    float bs = bias[co];
    #pragma unroll
    for (int i = 0; i < 2; ++i) {
      int hh = h0 + wn * 2 + i;
      float4 o;
      o.x = acc[i][j][0] + bs; o.y = acc[i][j][1] + bs;
      o.z = acc[i][j][2] + bs; o.w = acc[i][j][3] + bs;
      *reinterpret_cast<float4*>(&out[(size_t)(b * 64 + co) * 4096 + d0 * 256 + hh * 16 + lg * 4]) = o;
    }
  }
}

// ---------------- groupnorm stats ----------------
__global__ __launch_bounds__(256) void gn_stats1_k(const float* __restrict__ t, float* __restrict__ pt) {
  int blk = blockIdx.x;
  const float4* base = reinterpret_cast<const float4*>(t + (size_t)blk * 4096);
  float s = 0.f, ss = 0.f;
  for (int i = threadIdx.x; i < 1024; i += 256) {
    float4 v = base[i];
    s += v.x + v.y + v.z + v.w;
    ss = fmaf(v.x, v.x, ss); ss = fmaf(v.y, v.y, ss);
    ss = fmaf(v.z, v.z, ss); ss = fmaf(v.w, v.w, ss);
  }
  __shared__ float sh[512];
  sh[threadIdx.x] = s; sh[256 + threadIdx.x] = ss;
  __syncthreads();
  for (int stp = 128; stp > 0; stp >>= 1) {
    if (threadIdx.x < stp) {
      sh[threadIdx.x] += sh[threadIdx.x + stp];
      sh[256 + threadIdx.x] += sh[256 + threadIdx.x + stp];
    }
    __syncthreads();
  }
  if (threadIdx.x == 0) { pt[blk * 2] = sh[0]; pt[blk * 2 + 1] = sh[256]; }
}

__global__ __launch_bounds__(64) void gn_stats2_k(const float* __restrict__ pt, float* __restrict__ st) {
  int t = threadIdx.x;
  if (t < 16) {
    float s = 0.f, ss = 0.f;
    for (int i = 0; i < 16; ++i) { s += pt[(t * 16 + i) * 2]; ss += pt[(t * 16 + i) * 2 + 1]; }
    float m = s * (1.f / 65536.f);
    float var = ss * (1.f / 65536.f) - m * m;
    st[t * 2] = m;
    st[t * 2 + 1] = rsqrtf(var + 1e-5f);
  }
}

// ---------------- groupnorm apply + relu ----------------
__global__ __launch_bounds__(256) void gn_apply_k(const float* __restrict__ t, const float* __restrict__ st,
    const float* __restrict__ gamma, const float* __restrict__ beta, float* __restrict__ out) {
  int idx = blockIdx.x * 256 + threadIdx.x;
  int c = (idx >> 12) & 63, b = idx >> 18;
  int bg = b * 4 + (c >> 4);
  float m = st[bg * 2], r = st[bg * 2 + 1];
  float v = (t[idx] - m) * r * gamma[c] + beta[c];
  out[idx] = fmaxf(v, 0.f);
}

// ---------------- q/k projection -> bf16 [b][n][32] (scale folds log2e into Q) ----------------
__global__ __launch_bounds__(256) void proj_qk_k(const float* __restrict__ x1, const float* __restrict__ w,
    const float* __restrict__ bias, float scale, ushort* __restrict__ out) {
  int idx = blockIdx.x * 256 + threadIdx.x;
  int o = (idx >> 12) & 15, b = idx >> 16, n = idx & 4095;
  const float* xb = x1 + b * 262144 + n;
  const float* wr = w + o * 64;
  float acc = bias[o];
  #pragma unroll
  for (int c = 0; c < 64; ++c) acc = fmaf(wr[c], xb[c << 12], acc);
  out[(size_t)(b * 4096 + n) * 32 + o] = f2bf(acc * scale);
  out[(size_t)(b * 4096 + n) * 32 + 16 + o] = 0;
}

// ---------------- v projection -> bf16 [b][c][n] ----------------
__global__ __launch_bounds__(256) void proj_v_k(const float* __restrict__ x1, const float* __restrict__ w,
    const float* __restrict__ bias, ushort* __restrict__ out) {
  int idx = blockIdx.x * 256 + threadIdx.x;
  int o = (idx >> 12) & 63, b = idx >> 18, n = idx & 4095;
  const float* xb = x1 + b * 262144 + n;
  const float* wr = w + o * 64;
  float acc = bias[o];
  #pragma unroll
  for (int c = 0; c < 64; ++c) acc = fmaf(wr[c], xb[c << 12], acc);
  out[idx] = f2bf(acc);
}

// ---------------- flash spatial attention, bf16 MFMA, double-buffered 1-barrier ----------------
#define KP 40
#define VP 72
__global__ __launch_bounds__(256) void flash_mfma_k(const ushort* __restrict__ qt,
    const ushort* __restrict__ kt, const ushort* __restrict__ vb, float* __restrict__ sa) {
  __shared__ __align__(16) ushort kls[2][64 * KP];
  __shared__ __align__(16) ushort vls[2][64 * VP];
  __shared__ __align__(16) ushort pls[64 * VP];
  int b = blockIdx.x >> 6;
  int m0 = (blockIdx.x & 63) * 64;
  int tid = threadIdx.x;
  int w = tid >> 6, l = tid & 63;
  int lm = l & 15, lg = l >> 4;

  short8v qf = *reinterpret_cast<const short8v*>(
      qt + (size_t)(b * 4096 + m0 + w * 16 + lm) * 32 + lg * 8);

  f32x4 acc[4] = {};
  float M = -1e30f, S = 0.f;

  int sr = tid >> 2, sq = tid & 3;
  const ushort* ksrc = kt + (size_t)b * 4096 * 32 + (size_t)sr * 32 + sq * 8;
  const ushort* vsrc = vb + (size_t)b * 64 * 4096 + (size_t)sr * 4096 + sq * 16;
  int koff = sr * KP + sq * 8;
  int voff = sr * VP + sq * 16;

  // prologue: stage tile 0 into buf 0
  {
    short8v kr = *reinterpret_cast<const short8v*>(ksrc);
    short8v v0 = *reinterpret_cast<const short8v*>(vsrc);
    short8v v1 = *reinterpret_cast<const short8v*>(vsrc + 8);
    *reinterpret_cast<short8v*>(&kls[0][koff]) = kr;
    *reinterpret_cast<short8v*>(&vls[0][voff]) = v0;
    *reinterpret_cast<short8v*>(&vls[0][voff + 8]) = v1;
  }

  ushort* plb = &pls[(w * 16 + lm) * VP];

  #pragma unroll 2
  for (int it = 0; it < 64; ++it) {
    int cur = it & 1;
    // issue next-tile global loads early (in flight across barrier + compute)
    int nx = it < 63 ? it + 1 : 63;
    short8v knr = *reinterpret_cast<const short8v*>(ksrc + (size_t)nx * 2048);
    short8v vn0 = *reinterpret_cast<const short8v*>(vsrc + nx * 64);
    short8v vn1 = *reinterpret_cast<const short8v*>(vsrc + nx * 64 + 8);

    __syncthreads();   // buf[cur] staged; everyone done reading buf[cur^1]

    const ushort* kb  = &kls[cur][0];
    const ushort* vbk = &vls[cur][0];

    // QK^T: S[n][m]
    f32x4 sf[4];
    #pragma unroll
    for (int nt = 0; nt < 4; ++nt) {
      short8v kf = *reinterpret_cast<const short8v*>(&kb[(nt * 16 + lm) * KP + lg * 8]);
      f32x4 z = {};
      sf[nt] = __builtin_amdgcn_mfma_f32_16x16x32_bf16(kf, qf, z, 0, 0, 0);
    }

    // online softmax (base-2 domain; log2e folded into Q)
    float tmax = -1e30f;
    #pragma unroll
    for (int nt = 0; nt < 4; ++nt)
      #pragma unroll
      for (int r = 0; r < 4; ++r) tmax = fmaxf(tmax, sf[nt][r]);
    tmax = fmaxf(tmax, __shfl_xor(tmax, 16));
    tmax = fmaxf(tmax, __shfl_xor(tmax, 32));
    if (!__all(tmax <= M)) {            // defer-max: skip rescale when no growth
      float Mn = fmaxf(M, tmax);
      float sc = __builtin_amdgcn_exp2f(M - Mn);
      M = Mn;
      S *= sc;
      #pragma unroll
      for (int ct = 0; ct < 4; ++ct)
        #pragma unroll
        for (int r = 0; r < 4; ++r) acc[ct][r] *= sc;
    }
    float tsum = 0.f;
    float p[16];
    #pragma unroll
    for (int nt = 0; nt < 4; ++nt)
      #pragma unroll
      for (int r = 0; r < 4; ++r) {
        float e = __builtin_amdgcn_exp2f(sf[nt][r] - M);
        p[nt * 4 + r] = e;
        tsum += e;
      }
    tsum += __shfl_xor(tsum, 16);
    tsum += __shfl_xor(tsum, 32);
    S += tsum;

    // pack P -> bf16 via cvt_pk, write wave-private LDS rows
    #pragma unroll
    for (int nt = 0; nt < 4; ++nt) {
      unsigned p01, p23;
      asm("v_cvt_pk_bf16_f32 %0, %1, %2" : "=v"(p01) : "v"(p[nt * 4 + 0]), "v"(p[nt * 4 + 1]));
      asm("v_cvt_pk_bf16_f32 %0, %1, %2" : "=v"(p23) : "v"(p[nt * 4 + 2]), "v"(p[nt * 4 + 3]));
      union { unsigned u[2]; short4v v; } pk;
      pk.u[0] = p01; pk.u[1] = p23;
      *reinterpret_cast<short4v*>(plb + nt * 16 + lg * 4) = pk.v;
    }
    asm volatile("s_waitcnt lgkmcnt(0)" ::: "memory");
    __builtin_amdgcn_sched_barrier(0);

    // PV: acc[c][m] += V[c][n] * P[n][m]
    #pragma unroll
    for (int nh = 0; nh < 2; ++nh) {
      short8v pf = *reinterpret_cast<const short8v*>(plb + nh * 32 + lg * 8);
      #pragma unroll
      for (int ct = 0; ct < 4; ++ct) {
        short8v vf = *reinterpret_cast<const short8v*>(&vbk[(ct * 16 + lm) * VP + nh * 32 + lg * 8]);
        acc[ct] = __builtin_amdgcn_mfma_f32_16x16x32_bf16(vf, pf, acc[ct], 0, 0, 0);
      }
    }

    // tail: write prefetched tile into the other buffer
    if (it < 63) {
      *reinterpret_cast<short8v*>(&kls[cur ^ 1][koff]) = knr;
      *reinterpret_cast<short8v*>(&vls[cur ^ 1][voff]) = vn0;
      *reinterpret_cast<short8v*>(&vls[cur ^ 1][voff + 8]) = vn1;
    }
  }

  float inv = 1.f / S;
  #pragma unroll
  for (int ct = 0; ct < 4; ++ct)
    #pragma unroll
    for (int r = 0; r < 4; ++r)
      sa[(size_t)(b * 64 + ct * 16 + lg * 4 + r) * 4096 + m0 + w * 16 + lm] = acc[ct][r] * inv;
}

// ---------------- channel gram partials: hi/lo bf16 MFMA ----------------
__global__ __launch_bounds__(256) void gram_partial_k(const float* __restrict__ x1, float* __restrict__ pg) {
  __shared__ __align__(16) ushort hi[64 * 64];
  __shared__ __align__(16) ushort lo[64 * 64];
  int b = blockIdx.x >> 3, ks = blockIdx.x & 7;
  int tid = threadIdx.x;
  int wv = tid >> 6, l = tid & 63, lm = l & 15, lg = l >> 4;
  int wr = wv >> 1, wd = wv & 1;
  f32x4 acc[2][2] = {};
  int sr = tid >> 2, sq = tid & 3;
  const float* xb = x1 + (size_t)b * 262144;

  for (int kt = 0; kt < 8; ++kt) {
    int n0 = ks * 512 + kt * 64;
    __syncthreads();
    const float* src = xb + (size_t)sr * 4096 + n0 + sq * 16;
    #pragma unroll
    for (int c2 = 0; c2 < 2; ++c2) {
      int chunk = sq * 2 + c2;
      int dchunk = chunk ^ (sr & 7);
      short8v hvv, lvv;
      #pragma unroll
      for (int j = 0; j < 8; ++j) {
        float v = src[c2 * 8 + j];
        ushort hb = f2bf(v);
        union { float f; unsigned u; } uu; uu.u = ((unsigned)hb) << 16;
        hvv[j] = (short)hb;
        lvv[j] = (short)f2bf(v - uu.f);
      }
      *reinterpret_cast<short8v*>(&hi[sr * 64 + dchunk * 8]) = hvv;
      *reinterpret_cast<short8v*>(&lo[sr * 64 + dchunk * 8]) = lvv;
    }
    __syncthreads();
    #pragma unroll
    for (int kk = 0; kk < 2; ++kk) {
      short8v ah[2], al[2], bh[2], bl[2];
      #pragma unroll
      for (int i = 0; i < 2; ++i) {
        int rc = wr * 32 + i * 16 + lm;
        int ca = ((kk * 4 + lg) ^ (rc & 7)) * 8;
        ah[i] = *reinterpret_cast<const short8v*>(&hi[rc * 64 + ca]);
        al[i] = *reinterpret_cast<const short8v*>(&lo[rc * 64 + ca]);
        int rd = wd * 32 + i * 16 + lm;
        int cb = ((kk * 4 + lg) ^ (rd & 7)) * 8;
        bh[i] = *reinterpret_cast<const short8v*>(&hi[rd * 64 + cb]);
        bl[i] = *reinterpret_cast<const short8v*>(&lo[rd * 64 + cb]);
      }
      #pragma unroll
      for (int i = 0; i < 2; ++i)
        #pragma unroll
        for (int j = 0; j < 2; ++j) {
          acc[i][j] = __builtin_amdgcn_mfma_f32_16x16x32_bf16(ah[i], bh[j], acc[i][j], 0, 0, 0);
          acc[i][j] = __builtin_amdgcn_mfma_f32_16x16x32_bf16(ah[i], bl[j], acc[i][j], 0, 0, 0);
          acc[i][j] = __builtin_amdgcn_mfma_f32_16x16x32_bf16(al[i], bh[j], acc[i][j], 0, 0, 0);
        }
    }
  }
  float* pgb = pg + (size_t)blockIdx.x * 4096;
  #pragma unroll
  for (int i = 0; i < 2; ++i)
    #pragma unroll
    for (int j = 0; j < 2; ++j)
      #pragma unroll
      for (int r = 0; r < 4; ++r) {
        int c = wr * 32 + i * 16 + lg * 4 + r;
        int d = wd * 32 + j * 16 + lm;
        pgb[c * 64 + d] = acc[i][j][r];
      }
}

// ---------------- reduce partials + row softmax -> Ac[b][c][d] ----------------
__global__ __launch_bounds__(256) void gram_softmax_k(const float* __restrict__ pg, float* __restrict__ Ac) {
  int b = blockIdx.x;
  int t = threadIdx.x;
  int r = t >> 2, q = t & 3;
  float4 s[4] = {};
  for (int ks = 0; ks < 8; ++ks) {
    const float* row = pg + ((size_t)(b * 8 + ks) * 64 + r) * 64 + q * 16;
    #pragma unroll
    for (int i = 0; i < 4; ++i) {
      float4 v = *reinterpret_cast<const float4*>(row + i * 4);
      s[i].x += v.x; s[i].y += v.y; s[i].z += v.z; s[i].w += v.w;
    }
  }
  float mx = -1e30f;
  #pragma unroll
  for (int i = 0; i < 4; ++i)
    mx = fmaxf(mx, fmaxf(fmaxf(s[i].x, s[i].y), fmaxf(s[i].z, s[i].w)));
  mx = fmaxf(mx, __shfl_xor(mx, 1));
  mx = fmaxf(mx, __shfl_xor(mx, 2));
  float sum = 0.f;
  #pragma unroll
  for (int i = 0; i < 4; ++i) {
    s[i].x = __expf(s[i].x - mx); s[i].y = __expf(s[i].y - mx);
    s[i].z = __expf(s[i].z - mx); s[i].w = __expf(s[i].w - mx);
    sum += s[i].x + s[i].y + s[i].z + s[i].w;
  }
  sum += __shfl_xor(sum, 1);
  sum += __shfl_xor(sum, 2);
  float inv = 1.f / sum;
  float* dst = Ac + ((size_t)(b * 64 + r)) * 64 + q * 16;
  #pragma unroll
  for (int i = 0; i < 4; ++i) {
    float4 o; o.x = s[i].x * inv; o.y = s[i].y * inv; o.z = s[i].z * inv; o.w = s[i].w * inv;
    *reinterpret_cast<float4*>(dst + i * 4) = o;
  }
}

// ---------------- y = x1 + sa + Ac @ x1 -> bf16 transposed [b][n][ci] ----------------
__global__ __launch_bounds__(256) void ca_apply_k(const float* __restrict__ x1, const float* __restrict__ Ac,
    const float* __restrict__ sa, ushort* __restrict__ yt) {
  int idx = blockIdx.x * 256 + threadIdx.x;
  int n = idx & 4095, c = (idx >> 12) & 63, b = idx >> 18;
  const float* xb = x1 + b * 262144 + n;
  const float* ar = Ac + (b * 64 + c) * 64;
  float acc = x1[idx] + sa[idx];
  #pragma unroll
  for (int d = 0; d < 64; ++d) acc = fmaf(ar[d], xb[d << 12], acc);
  yt[(size_t)(b * 4096 + n) * 64 + c] = f2bf(acc);
}

extern "C" void kernel_launch(void* const* d_in, const int* in_sizes, int n_in,
                              void* d_out, int out_size, void* d_ws, size_t ws_size,
                              hipStream_t stream) {
  const float* x       = (const float*)d_in[0];
  const float* w_i     = (const float*)d_in[1];
  const float* b_i     = (const float*)d_in[2];
  const float* gamma_i = (const float*)d_in[3];
  const float* beta_i  = (const float*)d_in[4];
  const float* w_q     = (const float*)d_in[5];
  const float* b_q     = (const float*)d_in[6];
  const float* w_k     = (const float*)d_in[7];
  const float* b_k     = (const float*)d_in[8];
  const float* w_v     = (const float*)d_in[9];
  const float* b_v     = (const float*)d_in[10];
  const float* w_o     = (const float*)d_in[11];
  const float* b_o     = (const float*)d_in[12];
  const float* gamma_o = (const float*)d_in[13];
  const float* beta_o  = (const float*)d_in[14];
  float* ws = (float*)d_ws;
  float* t0 = ws + OFF_T0;
  float* x1 = ws + OFF_X1;
  ushort* qt  = (ushort*)(ws + OFF_QT);
  ushort* kt  = (ushort*)(ws + OFF_KT);
  ushort* vbp = (ushort*)(ws + OFF_VB);
  float* yb = ws + OFF_T0;             // sa aliases t0
  float* pg = ws + OFF_QT;             // gram partials alias qt (dead after flash)
  ushort* ytp = (ushort*)(ws + OFF_YT);
  ushort* xbp = (ushort*)(ws + OFF_XB);
  float* ac = ws + OFF_AC;
  ushort* wbi = (ushort*)(ws + OFF_WBI);
  ushort* wbo = (ushort*)(ws + OFF_WBO);
  float* pt = ws + OFF_PT;
  float* st = ws + OFF_ST;
  float* outp = (float*)d_out;

  wcvt_k<<<432, 256, 0, stream>>>(w_i, wbi);
  wcvt_k<<<432, 256, 0, stream>>>(w_o, wbo);
  xcvt_k<<<256, 256, 0, stream>>>(x, xbp);

  conv_mfma_k<<<256, 256, 0, stream>>>(xbp, wbi, b_i, t0);
  gn_stats1_k<<<256, 256, 0, stream>>>(t0, pt);
  gn_stats2_k<<<1, 64, 0, stream>>>(pt, st);
  gn_apply_k<<<4096, 256, 0, stream>>>(t0, st, gamma_i, beta_i, x1);

  proj_qk_k<<<1024, 256, 0, stream>>>(x1, w_q, b_q, 1.4426950408889634f, qt);
  proj_qk_k<<<1024, 256, 0, stream>>>(x1, w_k, b_k, 1.0f, kt);
  proj_v_k<<<4096, 256, 0, stream>>>(x1, w_v, b_v, vbp);

  flash_mfma_k<<<256, 256, 0, stream>>>(qt, kt, vbp, yb);

  gram_partial_k<<<32, 256, 0, stream>>>(x1, pg);
  gram_softmax_k<<<4, 256, 0, stream>>>(pg, ac);
  ca_apply_k<<<4096, 256, 0, stream>>>(x1, ac, yb, ytp);

  conv_mfma_k<<<256, 256, 0, stream>>>(ytp, wbo, b_o, t0);
  gn_stats1_k<<<256, 256, 0, stream>>>(t0, pt);
  gn_stats2_k<<<1, 64, 0, stream>>>(pt, st);
  gn_apply_k<<<4096, 256, 0, stream>>>(t0, st, gamma_o, beta_o, outp);
}

// Round 6
// 155.049 us; speedup vs baseline: 8.9787x; 1.1952x over previous
//
#include <hip/hip_runtime.h>

// workspace layout (float offsets); sa aliases t0; gram partials alias qt
#define OFF_T0  0
#define OFF_X1  1048576
#define OFF_QT  2097152
#define OFF_KT  2359296
#define OFF_VB  2621440
#define OFF_YT  3145728
#define OFF_XB  3670016
#define OFF_AC  4194304
#define OFF_WBI 4210688
#define OFF_WBO 4265984
#define OFF_PT  4321280
#define OFF_ST  4321792
#define OFF_PO  4325376              // split-flash acc partials: 1024 x 4096 f32
#define OFF_MS  8519680              // split-flash (M,S):       1024 x 128 f32
#define WS_NEED ((size_t)8650752 * 4)

typedef __attribute__((ext_vector_type(8))) short short8v;
typedef __attribute__((ext_vector_type(4))) short short4v;
typedef __attribute__((ext_vector_type(4))) float f32x4;

__device__ __forceinline__ ushort f2bf(float f) {
  union { float f; unsigned u; } v; v.f = f;
  unsigned r = (v.u + 0x7fffu + ((v.u >> 16) & 1u)) >> 16;
  return (ushort)r;
}

// ---------------- weight reorder: [co][ci][27] f32 -> [co][tap][ci] bf16 ----------------
__global__ __launch_bounds__(256) void wcvt_k(const float* __restrict__ w, ushort* __restrict__ wb) {
  int idx = blockIdx.x * 256 + threadIdx.x;
  int ci = idx & 63, tap = (idx >> 6) % 27, co = idx / (64 * 27);
  wb[idx] = f2bf(w[(co * 64 + ci) * 27 + tap]);
}

// ---------------- x convert: [b][ci][dhw] f32 -> [b][dhw][ci] bf16, tiled transpose ----------------
__global__ __launch_bounds__(256) void xcvt_k(const float* __restrict__ x, ushort* __restrict__ xb) {
  __shared__ ushort tl[64 * 72];
  int b = blockIdx.x >> 6;
  int n0 = (blockIdx.x & 63) * 64;
  int t = threadIdx.x;
  int ci = t >> 2, q = t & 3;
  const float* src = x + (size_t)(b * 64 + ci) * 4096 + n0 + q * 16;
  #pragma unroll
  for (int i = 0; i < 4; ++i) {
    float4 v = *reinterpret_cast<const float4*>(src + i * 4);
    tl[(q * 16 + i * 4 + 0) * 72 + ci] = f2bf(v.x);
    tl[(q * 16 + i * 4 + 1) * 72 + ci] = f2bf(v.y);
    tl[(q * 16 + i * 4 + 2) * 72 + ci] = f2bf(v.z);
    tl[(q * 16 + i * 4 + 3) * 72 + ci] = f2bf(v.w);
  }
  __syncthreads();
  int n = t >> 2, qq = t & 3;
  ushort* dst = xb + (size_t)(b * 4096 + n0 + n) * 64 + qq * 16;
  *reinterpret_cast<short8v*>(dst) = *reinterpret_cast<const short8v*>(&tl[n * 72 + qq * 16]);
  *reinterpret_cast<short8v*>(dst + 8) = *reinterpret_cast<const short8v*>(&tl[n * 72 + qq * 16 + 8]);
}

// ---------------- conv3d as implicit GEMM, bf16 MFMA ----------------
__global__ __launch_bounds__(256) void conv_mfma_k(const ushort* __restrict__ xt,
    const ushort* __restrict__ wb, const float* __restrict__ bias, float* __restrict__ out) {
  __shared__ __align__(16) ushort xls[18 * 18 * 64];
  int blk = blockIdx.x;
  int h0 = (blk & 3) * 4;
  int d0 = (blk >> 2) & 15;
  int b  = blk >> 6;
  int tid = threadIdx.x;

  const ushort* xtb = xt + (size_t)b * 4096 * 64;
  for (int u = tid; u < 324; u += 256) {
    int w_s = u % 18;
    int row = u / 18;
    int dz = row / 6, h_s = row - dz * 6;
    int d = d0 + dz - 1, h = h0 + h_s - 1, w = w_s - 1;
    ushort* dst = &xls[(row * 18 + w_s) * 64];
    int swz = w_s & 7;
    if (d >= 0 && d < 16 && h >= 0 && h < 16 && w >= 0 && w < 16) {
      const ushort* src = xtb + (size_t)(d * 256 + h * 16 + w) * 64;
      #pragma unroll
      for (int c = 0; c < 8; ++c)
        *reinterpret_cast<short8v*>(dst + ((c ^ swz) << 3)) =
            *reinterpret_cast<const short8v*>(src + (c << 3));
    } else {
      short8v z = {};
      #pragma unroll
      for (int c = 0; c < 8; ++c)
        *reinterpret_cast<short8v*>(dst + ((c ^ swz) << 3)) = z;
    }
  }
  __syncthreads();

  int wv = tid >> 6, l = tid & 63;
  int wn = wv >> 1, wc = wv & 1;
  int lm = l & 15, lg = l >> 4;

  f32x4 acc[2][2] = {};
  const ushort* wbase0 = wb + (size_t)((wc * 2 + 0) * 16 + lm) * 1728 + lg * 8;
  const ushort* wbase1 = wb + (size_t)((wc * 2 + 1) * 16 + lm) * 1728 + lg * 8;

  #pragma unroll 6
  for (int s = 0; s < 54; ++s) {
    int tap = s >> 1, c0h = s & 1;
    int dz = tap / 9, dyx = tap - dz * 9;
    int dy = dyx / 3, dx = dyx - dy * 3;
    int wrow = lm + dx;
    int chunk = ((c0h * 4 + lg) ^ (wrow & 7)) << 3;
    int r0 = ((dz * 6 + wn * 2 + dy) * 18 + wrow) * 64 + chunk;
    short8v a0 = *reinterpret_cast<const short8v*>(&xls[r0]);
    short8v a1 = *reinterpret_cast<const short8v*>(&xls[r0 + 18 * 64]);
    short8v b0 = *reinterpret_cast<const short8v*>(wbase0 + s * 32);
    short8v b1 = *reinterpret_cast<const short8v*>(wbase1 + s * 32);
    acc[0][0] = __builtin_amdgcn_mfma_f32_16x16x32_bf16(a0, b0, acc[0][0], 0, 0, 0);
    acc[0][1] = __builtin_amdgcn_mfma_f32_16x16x32_bf16(a0, b1, acc[0][1], 0, 0, 0);
    acc[1][0] = __builtin_amdgcn_mfma_f32_16x16x32_bf16(a1, b0, acc[1][0], 0, 0, 0);
    acc[1][1] = __builtin_amdgcn_mfma_f32_16x16x32_bf16(a1, b1, acc[1][1], 0, 0, 0);
  }

  #pragma unroll
  for (int j = 0; j < 2; ++j) {
    int co = (wc * 2 + j) * 16 + lm;
    float bs = bias[co];
    #pragma unroll
    for (int i = 0; i < 2; ++i) {
      int hh = h0 + wn * 2 + i;
      float4 o;
      o.x = acc[i][j][0] + bs; o.y = acc[i][j][1] + bs;
      o.z = acc[i][j][2] + bs; o.w = acc[i][j][3] + bs;
      *reinterpret_cast<float4*>(&out[(size_t)(b * 64 + co) * 4096 + d0 * 256 + hh * 16 + lg * 4]) = o;
    }
  }
}

// ---------------- groupnorm stats stage 1 ----------------
__global__ __launch_bounds__(256) void gn_stats1_k(const float* __restrict__ t, float* __restrict__ pt) {
  int blk = blockIdx.x;
  const float4* base = reinterpret_cast<const float4*>(t + (size_t)blk * 4096);
  float s = 0.f, ss = 0.f;
  for (int i = threadIdx.x; i < 1024; i += 256) {
    float4 v = base[i];
    s += v.x + v.y + v.z + v.w;
    ss = fmaf(v.x, v.x, ss); ss = fmaf(v.y, v.y, ss);
    ss = fmaf(v.z, v.z, ss); ss = fmaf(v.w, v.w, ss);
  }
  __shared__ float sh[512];
  sh[threadIdx.x] = s; sh[256 + threadIdx.x] = ss;
  __syncthreads();
  for (int stp = 128; stp > 0; stp >>= 1) {
    if (threadIdx.x < stp) {
      sh[threadIdx.x] += sh[threadIdx.x + stp];
      sh[256 + threadIdx.x] += sh[256 + threadIdx.x + stp];
    }
    __syncthreads();
  }
  if (threadIdx.x == 0) { pt[blk * 2] = sh[0]; pt[blk * 2 + 1] = sh[256]; }
}

// ---------------- groupnorm apply + relu (folds stage-2 reduction) ----------------
__global__ __launch_bounds__(256) void gn_apply_k(const float* __restrict__ t, const float* __restrict__ pt,
    const float* __restrict__ gamma, const float* __restrict__ beta, float* __restrict__ out) {
  __shared__ float sms[2];
  int idx = blockIdx.x * 256 + threadIdx.x;
  int c = (idx >> 12) & 63, b = idx >> 18;
  int bg = b * 4 + (c >> 4);
  if (threadIdx.x == 0) {
    float s = 0.f, ss = 0.f;
    #pragma unroll
    for (int i = 0; i < 16; ++i) { s += pt[bg * 32 + i * 2]; ss += pt[bg * 32 + i * 2 + 1]; }
    float m = s * (1.f / 65536.f);
    float var = ss * (1.f / 65536.f) - m * m;
    sms[0] = m; sms[1] = rsqrtf(var + 1e-5f);
  }
  __syncthreads();
  float v = (t[idx] - sms[0]) * sms[1] * gamma[c] + beta[c];
  out[idx] = fmaxf(v, 0.f);
}

// ---------------- fused q/k/v projections ----------------
__global__ __launch_bounds__(256) void proj_all_k(const float* __restrict__ x1,
    const float* __restrict__ wq, const float* __restrict__ bq,
    const float* __restrict__ wk, const float* __restrict__ bk,
    const float* __restrict__ wv, const float* __restrict__ bv,
    ushort* __restrict__ qt, ushort* __restrict__ kt, ushort* __restrict__ vt) {
  int blk = blockIdx.x;
  if (blk < 2048) {
    int idx = (blk & 1023) * 256 + threadIdx.x;
    int o = (idx >> 12) & 15, b = idx >> 16, n = idx & 4095;
    const float* w  = blk < 1024 ? wq : wk;
    const float* bb = blk < 1024 ? bq : bk;
    const float* xb = x1 + b * 262144 + n;
    const float* wr = w + o * 64;
    float acc = bb[o];
    #pragma unroll
    for (int c = 0; c < 64; ++c) acc = fmaf(wr[c], xb[c << 12], acc);
    float scale = blk < 1024 ? 1.4426950408889634f : 1.0f;
    ushort* out = blk < 1024 ? qt : kt;
    out[(size_t)(b * 4096 + n) * 32 + o] = f2bf(acc * scale);
    out[(size_t)(b * 4096 + n) * 32 + 16 + o] = 0;
  } else {
    int idx = (blk - 2048) * 256 + threadIdx.x;
    int o = (idx >> 12) & 63, b = idx >> 18, n = idx & 4095;
    const float* xb = x1 + b * 262144 + n;
    const float* wr = wv + o * 64;
    float acc = bv[o];
    #pragma unroll
    for (int c = 0; c < 64; ++c) acc = fmaf(wr[c], xb[c << 12], acc);
    vt[idx] = f2bf(acc);
  }
}

// ---------------- flash spatial attention, bf16 MFMA, double-buffered, optional split-K ----------------
#define KP 40
#define VP 72
template<bool SPLIT>
__global__ __launch_bounds__(256) void flash_mfma_k(const ushort* __restrict__ qt,
    const ushort* __restrict__ kt, const ushort* __restrict__ vb, float* __restrict__ sa,
    float* __restrict__ pacc, float* __restrict__ pms) {
  __shared__ __align__(16) ushort kls[2][64 * KP];
  __shared__ __align__(16) ushort vls[2][64 * VP];
  __shared__ __align__(16) ushort pls[64 * VP];
  int s, mt, b;
  if (SPLIT) { s = blockIdx.x & 3; mt = (blockIdx.x >> 2) & 63; b = blockIdx.x >> 8; }
  else       { s = 0; mt = blockIdx.x & 63; b = blockIdx.x >> 6; }
  const int NT = SPLIT ? 16 : 64;
  int m0 = mt * 64;
  int kofs = s * 1024;
  int tid = threadIdx.x;
  int w = tid >> 6, l = tid & 63;
  int lm = l & 15, lg = l >> 4;

  short8v qf = *reinterpret_cast<const short8v*>(
      qt + (size_t)(b * 4096 + m0 + w * 16 + lm) * 32 + lg * 8);

  f32x4 acc[4] = {};
  float M = -1e30f, S = 0.f;

  int sr = tid >> 2, sq = tid & 3;
  const ushort* ksrc = kt + (size_t)b * 4096 * 32 + (size_t)kofs * 32 + (size_t)sr * 32 + sq * 8;
  const ushort* vsrc = vb + (size_t)b * 64 * 4096 + (size_t)sr * 4096 + kofs + sq * 16;
  int koff = sr * KP + sq * 8;
  int voff = sr * VP + sq * 16;

  {
    short8v kr = *reinterpret_cast<const short8v*>(ksrc);
    short8v v0 = *reinterpret_cast<const short8v*>(vsrc);
    short8v v1 = *reinterpret_cast<const short8v*>(vsrc + 8);
    *reinterpret_cast<short8v*>(&kls[0][koff]) = kr;
    *reinterpret_cast<short8v*>(&vls[0][voff]) = v0;
    *reinterpret_cast<short8v*>(&vls[0][voff + 8]) = v1;
  }

  ushort* plb = &pls[(w * 16 + lm) * VP];

  #pragma unroll 2
  for (int it = 0; it < NT; ++it) {
    int cur = it & 1;
    int nx = it < NT - 1 ? it + 1 : NT - 1;
    short8v knr = *reinterpret_cast<const short8v*>(ksrc + (size_t)nx * 2048);
    short8v vn0 = *reinterpret_cast<const short8v*>(vsrc + nx * 64);
    short8v vn1 = *reinterpret_cast<const short8v*>(vsrc + nx * 64 + 8);

    __syncthreads();

    const ushort* kb  = &kls[cur][0];
    const ushort* vbk = &vls[cur][0];

    f32x4 sf[4];
    #pragma unroll
    for (int nt = 0; nt < 4; ++nt) {
      short8v kf = *reinterpret_cast<const short8v*>(&kb[(nt * 16 + lm) * KP + lg * 8]);
      f32x4 z = {};
      sf[nt] = __builtin_amdgcn_mfma_f32_16x16x32_bf16(kf, qf, z, 0, 0, 0);
    }

    float tmax = -1e30f;
    #pragma unroll
    for (int nt = 0; nt < 4; ++nt)
      #pragma unroll
      for (int r = 0; r < 4; ++r) tmax = fmaxf(tmax, sf[nt][r]);
    tmax = fmaxf(tmax, __shfl_xor(tmax, 16));
    tmax = fmaxf(tmax, __shfl_xor(tmax, 32));
    if (!__all(tmax <= M)) {
      float Mn = fmaxf(M, tmax);
      float sc = __builtin_amdgcn_exp2f(M - Mn);
      M = Mn;
      S *= sc;
      #pragma unroll
      for (int ct = 0; ct < 4; ++ct)
        #pragma unroll
        for (int r = 0; r < 4; ++r) acc[ct][r] *= sc;
    }
    float tsum = 0.f;
    float p[16];
    #pragma unroll
    for (int nt = 0; nt < 4; ++nt)
      #pragma unroll
      for (int r = 0; r < 4; ++r) {
        float e = __builtin_amdgcn_exp2f(sf[nt][r] - M);
        p[nt * 4 + r] = e;
        tsum += e;
      }
    tsum += __shfl_xor(tsum, 16);
    tsum += __shfl_xor(tsum, 32);
    S += tsum;

    #pragma unroll
    for (int nt = 0; nt < 4; ++nt) {
      unsigned p01, p23;
      asm("v_cvt_pk_bf16_f32 %0, %1, %2" : "=v"(p01) : "v"(p[nt * 4 + 0]), "v"(p[nt * 4 + 1]));
      asm("v_cvt_pk_bf16_f32 %0, %1, %2" : "=v"(p23) : "v"(p[nt * 4 + 2]), "v"(p[nt * 4 + 3]));
      union { unsigned u[2]; short4v v; } pk;
      pk.u[0] = p01; pk.u[1] = p23;
      *reinterpret_cast<short4v*>(plb + nt * 16 + lg * 4) = pk.v;
    }
    asm volatile("s_waitcnt lgkmcnt(0)" ::: "memory");
    __builtin_amdgcn_sched_barrier(0);

    #pragma unroll
    for (int nh = 0; nh < 2; ++nh) {
      short8v pf = *reinterpret_cast<const short8v*>(plb + nh * 32 + lg * 8);
      #pragma unroll
      for (int ct = 0; ct < 4; ++ct) {
        short8v vf = *reinterpret_cast<const short8v*>(&vbk[(ct * 16 + lm) * VP + nh * 32 + lg * 8]);
        acc[ct] = __builtin_amdgcn_mfma_f32_16x16x32_bf16(vf, pf, acc[ct], 0, 0, 0);
      }
    }

    if (it < NT - 1) {
      *reinterpret_cast<short8v*>(&kls[cur ^ 1][koff]) = knr;
      *reinterpret_cast<short8v*>(&vls[cur ^ 1][voff]) = vn0;
      *reinterpret_cast<short8v*>(&vls[cur ^ 1][voff + 8]) = vn1;
    }
  }

  if (SPLIT) {
    int blk = (b * 64 + mt) * 4 + s;
    float* pa = pacc + (size_t)blk * 4096;
    #pragma unroll
    for (int ct = 0; ct < 4; ++ct)
      #pragma unroll
      for (int r = 0; r < 4; ++r)
        pa[(ct * 16 + lg * 4 + r) * 64 + w * 16 + lm] = acc[ct][r];
    if (l < 16) {
      pms[(size_t)blk * 128 + (w * 16 + lm) * 2]     = M;
      pms[(size_t)blk * 128 + (w * 16 + lm) * 2 + 1] = S;
    }
  } else {
    float inv = 1.f / S;
    #pragma unroll
    for (int ct = 0; ct < 4; ++ct)
      #pragma unroll
      for (int r = 0; r < 4; ++r)
        sa[(size_t)(b * 64 + ct * 16 + lg * 4 + r) * 4096 + m0 + w * 16 + lm] = acc[ct][r] * inv;
  }
}

// ---------------- channel gram partials: hi/lo bf16 MFMA ----------------
__global__ __launch_bounds__(256) void gram_partial_k(const float* __restrict__ x1, float* __restrict__ pg) {
  __shared__ __align__(16) ushort hi[64 * 64];
  __shared__ __align__(16) ushort lo[64 * 64];
  int b = blockIdx.x >> 3, ks = blockIdx.x & 7;
  int tid = threadIdx.x;
  int wv = tid >> 6, l = tid & 63, lm = l & 15, lg = l >> 4;
  int wr = wv >> 1, wd = wv & 1;
  f32x4 acc[2][2] = {};
  int sr = tid >> 2, sq = tid & 3;
  const float* xb = x1 + (size_t)b * 262144;

  for (int kt = 0; kt < 8; ++kt) {
    int n0 = ks * 512 + kt * 64;
    __syncthreads();
    const float* src = xb + (size_t)sr * 4096 + n0 + sq * 16;
    #pragma unroll
    for (int c2 = 0; c2 < 2; ++c2) {
      int chunk = sq * 2 + c2;
      int dchunk = chunk ^ (sr & 7);
      short8v hvv, lvv;
      #pragma unroll
      for (int j = 0; j < 8; ++j) {
        float v = src[c2 * 8 + j];
        ushort hb = f2bf(v);
        union { float f; unsigned u; } uu; uu.u = ((unsigned)hb) << 16;
        hvv[j] = (short)hb;
        lvv[j] = (short)f2bf(v - uu.f);
      }
      *reinterpret_cast<short8v*>(&hi[sr * 64 + dchunk * 8]) = hvv;
      *reinterpret_cast<short8v*>(&lo[sr * 64 + dchunk * 8]) = lvv;
    }
    __syncthreads();
    #pragma unroll
    for (int kk = 0; kk < 2; ++kk) {
      short8v ah[2], al[2], bh[2], bl[2];
      #pragma unroll
      for (int i = 0; i < 2; ++i) {
        int rc = wr * 32 + i * 16 + lm;
        int ca = ((kk * 4 + lg) ^ (rc & 7)) * 8;
        ah[i] = *reinterpret_cast<const short8v*>(&hi[rc * 64 + ca]);
        al[i] = *reinterpret_cast<const short8v*>(&lo[rc * 64 + ca]);
        int rd = wd * 32 + i * 16 + lm;
        int cb = ((kk * 4 + lg) ^ (rd & 7)) * 8;
        bh[i] = *reinterpret_cast<const short8v*>(&hi[rd * 64 + cb]);
        bl[i] = *reinterpret_cast<const short8v*>(&lo[rd * 64 + cb]);
      }
      #pragma unroll
      for (int i = 0; i < 2; ++i)
        #pragma unroll
        for (int j = 0; j < 2; ++j) {
          acc[i][j] = __builtin_amdgcn_mfma_f32_16x16x32_bf16(ah[i], bh[j], acc[i][j], 0, 0, 0);
          acc[i][j] = __builtin_amdgcn_mfma_f32_16x16x32_bf16(ah[i], bl[j], acc[i][j], 0, 0, 0);
          acc[i][j] = __builtin_amdgcn_mfma_f32_16x16x32_bf16(al[i], bh[j], acc[i][j], 0, 0, 0);
        }
    }
  }
  float* pgb = pg + (size_t)blockIdx.x * 4096;
  #pragma unroll
  for (int i = 0; i < 2; ++i)
    #pragma unroll
    for (int j = 0; j < 2; ++j)
      #pragma unroll
      for (int r = 0; r < 4; ++r) {
        int c = wr * 32 + i * 16 + lg * 4 + r;
        int d = wd * 32 + j * 16 + lm;
        pgb[c * 64 + d] = acc[i][j][r];
      }
}

// ---------------- reduce partials + row softmax -> Ac[b][c][d] ----------------
__global__ __launch_bounds__(256) void gram_softmax_k(const float* __restrict__ pg, float* __restrict__ Ac) {
  int b = blockIdx.x;
  int t = threadIdx.x;
  int r = t >> 2, q = t & 3;
  float4 s[4] = {};
  for (int ks = 0; ks < 8; ++ks) {
    const float* row = pg + ((size_t)(b * 8 + ks) * 64 + r) * 64 + q * 16;
    #pragma unroll
    for (int i = 0; i < 4; ++i) {
      float4 v = *reinterpret_cast<const float4*>(row + i * 4);
      s[i].x += v.x; s[i].y += v.y; s[i].z += v.z; s[i].w += v.w;
    }
  }
  float mx = -1e30f;
  #pragma unroll
  for (int i = 0; i < 4; ++i)
    mx = fmaxf(mx, fmaxf(fmaxf(s[i].x, s[i].y), fmaxf(s[i].z, s[i].w)));
  mx = fmaxf(mx, __shfl_xor(mx, 1));
  mx = fmaxf(mx, __shfl_xor(mx, 2));
  float sum = 0.f;
  #pragma unroll
  for (int i = 0; i < 4; ++i) {
    s[i].x = __expf(s[i].x - mx); s[i].y = __expf(s[i].y - mx);
    s[i].z = __expf(s[i].z - mx); s[i].w = __expf(s[i].w - mx);
    sum += s[i].x + s[i].y + s[i].z + s[i].w;
  }
  sum += __shfl_xor(sum, 1);
  sum += __shfl_xor(sum, 2);
  float inv = 1.f / sum;
  float* dst = Ac + ((size_t)(b * 64 + r)) * 64 + q * 16;
  #pragma unroll
  for (int i = 0; i < 4; ++i) {
    float4 o; o.x = s[i].x * inv; o.y = s[i].y * inv; o.z = s[i].z * inv; o.w = s[i].w * inv;
    *reinterpret_cast<float4*>(dst + i * 4) = o;
  }
}

// ---------------- y = x1 + sa(+combine) + Ac @ x1 -> bf16 [b][n][ci] ----------------
template<int NSPLIT>
__global__ __launch_bounds__(256) void ca_apply_k(const float* __restrict__ x1, const float* __restrict__ Ac,
    const float* __restrict__ sa, const float* __restrict__ pacc, const float* __restrict__ pms,
    ushort* __restrict__ yt) {
  __shared__ float x1f[64 * 72];
  __shared__ float acf[64 * 72];
  __shared__ float wls[4 * 64];
  int b = blockIdx.x >> 6, mt = blockIdx.x & 63;
  int n0 = mt * 64;
  int tid = threadIdx.x;
  {
    int d = tid >> 2, q = tid & 3;
    const float* xs = x1 + (size_t)(b * 64 + d) * 4096 + n0 + q * 16;
    const float* as = Ac + (size_t)(b * 64 + d) * 64 + q * 16;
    #pragma unroll
    for (int i = 0; i < 4; ++i) {
      float4 v = *reinterpret_cast<const float4*>(xs + i * 4);
      x1f[d * 72 + q * 16 + i * 4 + 0] = v.x;
      x1f[d * 72 + q * 16 + i * 4 + 1] = v.y;
      x1f[d * 72 + q * 16 + i * 4 + 2] = v.z;
      x1f[d * 72 + q * 16 + i * 4 + 3] = v.w;
      float4 a = *reinterpret_cast<const float4*>(as + i * 4);
      acf[d * 72 + q * 16 + i * 4 + 0] = a.x;
      acf[d * 72 + q * 16 + i * 4 + 1] = a.y;
      acf[d * 72 + q * 16 + i * 4 + 2] = a.z;
      acf[d * 72 + q * 16 + i * 4 + 3] = a.w;
    }
  }
  if (NSPLIT > 1 && tid < 64) {
    int m = tid;
    size_t msb = (size_t)(b * 64 + mt) * NSPLIT * 128;
    float Ms[NSPLIT], Ss[NSPLIT];
    float Mg = -1e30f;
    #pragma unroll
    for (int s = 0; s < NSPLIT; ++s) {
      Ms[s] = pms[msb + s * 128 + m * 2];
      Ss[s] = pms[msb + s * 128 + m * 2 + 1];
      Mg = fmaxf(Mg, Ms[s]);
    }
    float Stot = 0.f;
    #pragma unroll
    for (int s = 0; s < NSPLIT; ++s) {
      float wv = __builtin_amdgcn_exp2f(Ms[s] - Mg);
      wls[s * 64 + m] = wv;
      Stot += wv * Ss[s];
    }
    float inv = 1.f / Stot;
    #pragma unroll
    for (int s = 0; s < NSPLIT; ++s) wls[s * 64 + m] *= inv;
  }
  __syncthreads();
  int m = tid & 63, cg = tid >> 6;
  float sval[16];
  if (NSPLIT > 1) {
    #pragma unroll
    for (int ci = 0; ci < 16; ++ci) sval[ci] = 0.f;
    const float* pb = pacc + (size_t)(b * 64 + mt) * NSPLIT * 4096;
    #pragma unroll
    for (int s = 0; s < NSPLIT; ++s) {
      float wv = wls[s * 64 + m];
      #pragma unroll
      for (int ci = 0; ci < 16; ++ci)
        sval[ci] = fmaf(wv, pb[s * 4096 + (cg * 16 + ci) * 64 + m], sval[ci]);
    }
  } else {
    #pragma unroll
    for (int ci = 0; ci < 16; ++ci)
      sval[ci] = sa[(size_t)(b * 64 + cg * 16 + ci) * 4096 + n0 + m];
  }
  float xcol[64];
  #pragma unroll
  for (int d = 0; d < 64; ++d) xcol[d] = x1f[d * 72 + m];
  union { ushort u[16]; short8v v[2]; } pk;
  #pragma unroll
  for (int ci = 0; ci < 16; ++ci) {
    int c = cg * 16 + ci;
    float o = xcol[c] + sval[ci];
    const float* ar = &acf[c * 72];
    #pragma unroll
    for (int d4 = 0; d4 < 16; ++d4) {
      float4 a4 = *reinterpret_cast<const float4*>(ar + d4 * 4);
      o = fmaf(a4.x, xcol[d4 * 4 + 0], o);
      o = fmaf(a4.y, xcol[d4 * 4 + 1], o);
      o = fmaf(a4.z, xcol[d4 * 4 + 2], o);
      o = fmaf(a4.w, xcol[d4 * 4 + 3], o);
    }
    pk.u[ci] = f2bf(o);
  }
  ushort* dst = yt + (size_t)(b * 4096 + n0 + m) * 64 + cg * 16;
  *reinterpret_cast<short8v*>(dst) = pk.v[0];
  *reinterpret_cast<short8v*>(dst + 8) = pk.v[1];
}

extern "C" void kernel_launch(void* const* d_in, const int* in_sizes, int n_in,
                              void* d_out, int out_size, void* d_ws, size_t ws_size,
                              hipStream_t stream) {
  const float* x       = (const float*)d_in[0];
  const float* w_i     = (const float*)d_in[1];
  const float* b_i     = (const float*)d_in[2];
  const float* gamma_i = (const float*)d_in[3];
  const float* beta_i  = (const float*)d_in[4];
  const float* w_q     = (const float*)d_in[5];
  const float* b_q     = (const float*)d_in[6];
  const float* w_k     = (const float*)d_in[7];
  const float* b_k     = (const float*)d_in[8];
  const float* w_v     = (const float*)d_in[9];
  const float* b_v     = (const float*)d_in[10];
  const float* w_o     = (const float*)d_in[11];
  const float* b_o     = (const float*)d_in[12];
  const float* gamma_o = (const float*)d_in[13];
  const float* beta_o  = (const float*)d_in[14];
  float* ws = (float*)d_ws;
  float* t0 = ws + OFF_T0;
  float* x1 = ws + OFF_X1;
  ushort* qt  = (ushort*)(ws + OFF_QT);
  ushort* kt  = (ushort*)(ws + OFF_KT);
  ushort* vbp = (ushort*)(ws + OFF_VB);
  float* yb = ws + OFF_T0;             // sa aliases t0 (fallback path)
  float* pg = ws + OFF_QT;             // gram partials alias qt (dead after flash)
  ushort* ytp = (ushort*)(ws + OFF_YT);
  ushort* xbp = (ushort*)(ws + OFF_XB);
  float* ac = ws + OFF_AC;
  ushort* wbi = (ushort*)(ws + OFF_WBI);
  ushort* wbo = (ushort*)(ws + OFF_WBO);
  float* pt = ws + OFF_PT;
  float* pacc = ws + OFF_PO;
  float* pms  = ws + OFF_MS;
  float* outp = (float*)d_out;
  bool split = ws_size >= WS_NEED;

  wcvt_k<<<432, 256, 0, stream>>>(w_i, wbi);
  wcvt_k<<<432, 256, 0, stream>>>(w_o, wbo);
  xcvt_k<<<256, 256, 0, stream>>>(x, xbp);

  conv_mfma_k<<<256, 256, 0, stream>>>(xbp, wbi, b_i, t0);
  gn_stats1_k<<<256, 256, 0, stream>>>(t0, pt);
  gn_apply_k<<<4096, 256, 0, stream>>>(t0, pt, gamma_i, beta_i, x1);

  proj_all_k<<<6144, 256, 0, stream>>>(x1, w_q, b_q, w_k, b_k, w_v, b_v, qt, kt, vbp);

  if (split)
    flash_mfma_k<true><<<1024, 256, 0, stream>>>(qt, kt, vbp, yb, pacc, pms);
  else
    flash_mfma_k<false><<<256, 256, 0, stream>>>(qt, kt, vbp, yb, pacc, pms);

  gram_partial_k<<<32, 256, 0, stream>>>(x1, pg);
  gram_softmax_k<<<4, 256, 0, stream>>>(pg, ac);

  if (split)
    ca_apply_k<4><<<256, 256, 0, stream>>>(x1, ac, yb, pacc, pms, ytp);
  else
    ca_apply_k<1><<<256, 256, 0, stream>>>(x1, ac, yb, pacc, pms, ytp);

  conv_mfma_k<<<256, 256, 0, stream>>>(ytp, wbo, b_o, t0);
  gn_stats1_k<<<256, 256, 0, stream>>>(t0, pt);
  gn_apply_k<<<4096, 256, 0, stream>>>(t0, pt, gamma_o, beta_o, outp);
}

// Round 7
// 138.361 us; speedup vs baseline: 10.0616x; 1.1206x over previous
//
#include <hip/hip_runtime.h>

// workspace layout (float offsets)
#define OFF_T0  0            // conv out fp32 [b][c][n], 1M floats
#define OFF_SA  1048576      // fallback sa fp32, 1M floats (free in split mode)
#define OFF_QT  2097152      // q bf16 [b][n][32] (1 MB) ; gram pg aliases QT+KT (2 MB)
#define OFF_KT  2359296      // k bf16 [b][n][32]
#define OFF_VB  2621440      // v bf16 [b][c][n] (2 MB)
#define OFF_YT  3145728      // y bf16 [b][n][ci] (2 MB)
#define OFF_XB  3670016      // x bf16 [b][n][ci] (2 MB)
#define OFF_AC  4194304      // Ac fp32 [b][c][d] (64 KB)
#define OFF_WBI 4210688
#define OFF_WBO 4265984
#define OFF_PT  4321280      // GN sums: pt0[32], pt1[32]
#define OFF_PO  4325376      // split-flash acc partials bf16: 1024 x 4096 (8 MB)
#define OFF_MS  6422528      // split-flash (M,S): 1024 x 128 f32
#define WS_NEED ((size_t)6553600 * 4)

typedef __attribute__((ext_vector_type(8))) short short8v;
typedef __attribute__((ext_vector_type(4))) short short4v;
typedef __attribute__((ext_vector_type(4))) float f32x4;

__device__ __forceinline__ ushort f2bf(float f) {
  union { float f; unsigned u; } v; v.f = f;
  unsigned r = (v.u + 0x7fffu + ((v.u >> 16) & 1u)) >> 16;
  return (ushort)r;
}
__device__ __forceinline__ float bf2f(ushort u) {
  union { unsigned u; float f; } v; v.u = ((unsigned)u) << 16;
  return v.f;
}

// ---------------- both weight reorders: [co][ci][27] f32 -> [co][tap][ci] bf16 ----------------
__global__ __launch_bounds__(256) void wcvt2_k(const float* __restrict__ wi, const float* __restrict__ wo,
    ushort* __restrict__ wbi, ushort* __restrict__ wbo) {
  int idx = blockIdx.x * 256 + threadIdx.x;   // 2*110592
  const float* w = idx < 110592 ? wi : wo;
  ushort* wb = idx < 110592 ? wbi : wbo;
  int j = idx < 110592 ? idx : idx - 110592;
  int ci = j & 63, tap = (j >> 6) % 27, co = j / (64 * 27);
  wb[j] = f2bf(w[(co * 64 + ci) * 27 + tap]);
}

// ---------------- x convert: [b][ci][dhw] f32 -> [b][dhw][ci] bf16; zeroes pt ----------------
__global__ __launch_bounds__(256) void xcvt_k(const float* __restrict__ x, ushort* __restrict__ xb,
    float* __restrict__ pt) {
  if (blockIdx.x == 0 && threadIdx.x < 64) pt[threadIdx.x] = 0.f;
  __shared__ ushort tl[64 * 72];
  int b = blockIdx.x >> 6;
  int n0 = (blockIdx.x & 63) * 64;
  int t = threadIdx.x;
  int ci = t >> 2, q = t & 3;
  const float* src = x + (size_t)(b * 64 + ci) * 4096 + n0 + q * 16;
  #pragma unroll
  for (int i = 0; i < 4; ++i) {
    float4 v = *reinterpret_cast<const float4*>(src + i * 4);
    tl[(q * 16 + i * 4 + 0) * 72 + ci] = f2bf(v.x);
    tl[(q * 16 + i * 4 + 1) * 72 + ci] = f2bf(v.y);
    tl[(q * 16 + i * 4 + 2) * 72 + ci] = f2bf(v.z);
    tl[(q * 16 + i * 4 + 3) * 72 + ci] = f2bf(v.w);
  }
  __syncthreads();
  int n = t >> 2, qq = t & 3;
  ushort* dst = xb + (size_t)(b * 4096 + n0 + n) * 64 + qq * 16;
  *reinterpret_cast<short8v*>(dst) = *reinterpret_cast<const short8v*>(&tl[n * 72 + qq * 16]);
  *reinterpret_cast<short8v*>(dst + 8) = *reinterpret_cast<const short8v*>(&tl[n * 72 + qq * 16 + 8]);
}

// ---------------- conv3d implicit GEMM + GN-stats epilogue (atomics into ptg) ----------------
__global__ __launch_bounds__(256) void conv_mfma_k(const ushort* __restrict__ xt,
    const ushort* __restrict__ wb, const float* __restrict__ bias, float* __restrict__ out,
    float* __restrict__ ptg) {
  __shared__ __align__(16) ushort xls[18 * 18 * 64];
  __shared__ float sh_st[16];
  int blk = blockIdx.x;
  int h0 = (blk & 3) * 4;
  int d0 = (blk >> 2) & 15;
  int b  = blk >> 6;
  int tid = threadIdx.x;

  const ushort* xtb = xt + (size_t)b * 4096 * 64;
  for (int u = tid; u < 324; u += 256) {
    int w_s = u % 18;
    int row = u / 18;
    int dz = row / 6, h_s = row - dz * 6;
    int d = d0 + dz - 1, h = h0 + h_s - 1, w = w_s - 1;
    ushort* dst = &xls[(row * 18 + w_s) * 64];
    int swz = w_s & 7;
    if (d >= 0 && d < 16 && h >= 0 && h < 16 && w >= 0 && w < 16) {
      const ushort* src = xtb + (size_t)(d * 256 + h * 16 + w) * 64;
      #pragma unroll
      for (int c = 0; c < 8; ++c)
        *reinterpret_cast<short8v*>(dst + ((c ^ swz) << 3)) =
            *reinterpret_cast<const short8v*>(src + (c << 3));
    } else {
      short8v z = {};
      #pragma unroll
      for (int c = 0; c < 8; ++c)
        *reinterpret_cast<short8v*>(dst + ((c ^ swz) << 3)) = z;
    }
  }
  __syncthreads();

  int wv = tid >> 6, l = tid & 63;
  int wn = wv >> 1, wc = wv & 1;
  int lm = l & 15, lg = l >> 4;

  f32x4 acc[2][2] = {};
  const ushort* wbase0 = wb + (size_t)((wc * 2 + 0) * 16 + lm) * 1728 + lg * 8;
  const ushort* wbase1 = wb + (size_t)((wc * 2 + 1) * 16 + lm) * 1728 + lg * 8;

  #pragma unroll 6
  for (int s = 0; s < 54; ++s) {
    int tap = s >> 1, c0h = s & 1;
    int dz = tap / 9, dyx = tap - dz * 9;
    int dy = dyx / 3, dx = dyx - dy * 3;
    int wrow = lm + dx;
    int chunk = ((c0h * 4 + lg) ^ (wrow & 7)) << 3;
    int r0 = ((dz * 6 + wn * 2 + dy) * 18 + wrow) * 64 + chunk;
    short8v a0 = *reinterpret_cast<const short8v*>(&xls[r0]);
    short8v a1 = *reinterpret_cast<const short8v*>(&xls[r0 + 18 * 64]);
    short8v b0 = *reinterpret_cast<const short8v*>(wbase0 + s * 32);
    short8v b1 = *reinterpret_cast<const short8v*>(wbase1 + s * 32);
    acc[0][0] = __builtin_amdgcn_mfma_f32_16x16x32_bf16(a0, b0, acc[0][0], 0, 0, 0);
    acc[0][1] = __builtin_amdgcn_mfma_f32_16x16x32_bf16(a0, b1, acc[0][1], 0, 0, 0);
    acc[1][0] = __builtin_amdgcn_mfma_f32_16x16x32_bf16(a1, b0, acc[1][0], 0, 0, 0);
    acc[1][1] = __builtin_amdgcn_mfma_f32_16x16x32_bf16(a1, b1, acc[1][1], 0, 0, 0);
  }

  float gs[2], gss[2];
  #pragma unroll
  for (int j = 0; j < 2; ++j) {
    gs[j] = 0.f; gss[j] = 0.f;
    int co = (wc * 2 + j) * 16 + lm;
    float bs = bias[co];
    #pragma unroll
    for (int i = 0; i < 2; ++i) {
      int hh = h0 + wn * 2 + i;
      float4 o;
      o.x = acc[i][j][0] + bs; o.y = acc[i][j][1] + bs;
      o.z = acc[i][j][2] + bs; o.w = acc[i][j][3] + bs;
      gs[j]  += o.x + o.y + o.z + o.w;
      gss[j] = fmaf(o.x, o.x, gss[j]); gss[j] = fmaf(o.y, o.y, gss[j]);
      gss[j] = fmaf(o.z, o.z, gss[j]); gss[j] = fmaf(o.w, o.w, gss[j]);
      *reinterpret_cast<float4*>(&out[(size_t)(b * 64 + co) * 4096 + d0 * 256 + hh * 16 + lg * 4]) = o;
    }
  }
  #pragma unroll
  for (int j = 0; j < 2; ++j) {
    #pragma unroll
    for (int off = 32; off > 0; off >>= 1) {
      gs[j]  += __shfl_xor(gs[j], off);
      gss[j] += __shfl_xor(gss[j], off);
    }
    if (l == 0) { sh_st[wv * 4 + j * 2] = gs[j]; sh_st[wv * 4 + j * 2 + 1] = gss[j]; }
  }
  __syncthreads();
  if (tid < 8) {
    int g = tid >> 1, w2 = tid & 1;
    int wcg = g >> 1, j = g & 1;
    float v = sh_st[wcg * 4 + j * 2 + w2] + sh_st[(wcg + 2) * 4 + j * 2 + w2];
    atomicAdd(&ptg[(b * 4 + g) * 2 + w2], v);
  }
}

// ---------------- groupnorm apply + relu (final output) ----------------
__global__ __launch_bounds__(256) void gn_apply_k(const float* __restrict__ t, const float* __restrict__ pt,
    const float* __restrict__ gamma, const float* __restrict__ beta, float* __restrict__ out) {
  int idx = blockIdx.x * 256 + threadIdx.x;
  int c = (idx >> 12) & 63, b = idx >> 18;
  int bg = b * 4 + (c >> 4);
  float s0 = pt[bg * 2], ss0 = pt[bg * 2 + 1];
  float m = s0 * (1.f / 65536.f);
  float r = rsqrtf(ss0 * (1.f / 65536.f) - m * m + 1e-5f);
  float ga = r * gamma[c], bb2 = beta[c] - m * r * gamma[c];
  out[idx] = fmaxf(fmaf(t[idx], ga, bb2), 0.f);
}

// ---------------- fused q/k/v projections, LDS-tiled, GN inline ----------------
__global__ __launch_bounds__(256) void proj_all_k(const float* __restrict__ t0, const float* __restrict__ pt0,
    const float* __restrict__ gamma, const float* __restrict__ beta,
    const float* __restrict__ wq, const float* __restrict__ bq,
    const float* __restrict__ wk, const float* __restrict__ bk,
    const float* __restrict__ wv_, const float* __restrict__ bv,
    ushort* __restrict__ qt, ushort* __restrict__ kt, ushort* __restrict__ vt) {
  __shared__ float xls[64 * 68];
  int b = blockIdx.x >> 6, n0 = (blockIdx.x & 63) * 64;
  int tid = threadIdx.x;
  {
    int ci = tid >> 2, q = tid & 3;
    int bg = b * 4 + (ci >> 4);
    float s0 = pt0[bg * 2], ss0 = pt0[bg * 2 + 1];
    float m = s0 * (1.f / 65536.f);
    float rv = rsqrtf(ss0 * (1.f / 65536.f) - m * m + 1e-5f);
    float ga = rv * gamma[ci], bb2 = beta[ci] - m * rv * gamma[ci];
    const float* src = t0 + (size_t)(b * 64 + ci) * 4096 + n0 + q * 16;
    #pragma unroll
    for (int i = 0; i < 4; ++i) {
      float4 v = *reinterpret_cast<const float4*>(src + i * 4);
      float* d = &xls[ci * 68 + q * 16 + i * 4];
      d[0] = fmaxf(fmaf(v.x, ga, bb2), 0.f);
      d[1] = fmaxf(fmaf(v.y, ga, bb2), 0.f);
      d[2] = fmaxf(fmaf(v.z, ga, bb2), 0.f);
      d[3] = fmaxf(fmaf(v.w, ga, bb2), 0.f);
    }
  }
  __syncthreads();
  int n = tid & 63, og = tid >> 6;
  float xr[64];
  #pragma unroll
  for (int c = 0; c < 64; ++c) xr[c] = xls[c * 68 + n];
  if (og < 2) {
    const float* w  = og == 0 ? wq : wk;
    const float* bb = og == 0 ? bq : bk;
    float scale = og == 0 ? 1.4426950408889634f : 1.0f;
    ushort* outp = og == 0 ? qt : kt;
    union { ushort u[16]; short8v v[2]; } pk;
    #pragma unroll
    for (int o = 0; o < 16; ++o) {
      const float* wr = w + o * 64;
      float acc = bb[o];
      #pragma unroll
      for (int c = 0; c < 64; ++c) acc = fmaf(wr[c], xr[c], acc);
      pk.u[o] = f2bf(acc * scale);
    }
    ushort* dst = outp + (size_t)(b * 4096 + n0 + n) * 32;
    *reinterpret_cast<short8v*>(dst) = pk.v[0];
    *reinterpret_cast<short8v*>(dst + 8) = pk.v[1];
    short8v z = {};
    *reinterpret_cast<short8v*>(dst + 16) = z;
    *reinterpret_cast<short8v*>(dst + 24) = z;
  } else {
    int o0 = (og - 2) * 32;
    #pragma unroll
    for (int o = 0; o < 32; ++o) {
      const float* wr = wv_ + (o0 + o) * 64;
      float acc = bv[o0 + o];
      #pragma unroll
      for (int c = 0; c < 64; ++c) acc = fmaf(wr[c], xr[c], acc);
      vt[(size_t)(b * 64 + o0 + o) * 4096 + n0 + n] = f2bf(acc);
    }
  }
}

// ---------------- flash spatial attention, bf16 MFMA, double-buffered, optional split-K ----------------
#define KP 40
#define VP 72
template<bool SPLIT>
__global__ __launch_bounds__(256) void flash_mfma_k(const ushort* __restrict__ qt,
    const ushort* __restrict__ kt, const ushort* __restrict__ vb, float* __restrict__ sa,
    ushort* __restrict__ pacc, float* __restrict__ pms) {
  __shared__ __align__(16) ushort kls[2][64 * KP];
  __shared__ __align__(16) ushort vls[2][64 * VP];
  __shared__ __align__(16) ushort pls[64 * VP];
  int s, mt, b;
  if (SPLIT) { s = blockIdx.x & 3; mt = (blockIdx.x >> 2) & 63; b = blockIdx.x >> 8; }
  else       { s = 0; mt = blockIdx.x & 63; b = blockIdx.x >> 6; }
  const int NT = SPLIT ? 16 : 64;
  int m0 = mt * 64;
  int kofs = s * 1024;
  int tid = threadIdx.x;
  int w = tid >> 6, l = tid & 63;
  int lm = l & 15, lg = l >> 4;

  short8v qf = *reinterpret_cast<const short8v*>(
      qt + (size_t)(b * 4096 + m0 + w * 16 + lm) * 32 + lg * 8);

  f32x4 acc[4] = {};
  float M = -1e30f, S = 0.f;

  int sr = tid >> 2, sq = tid & 3;
  const ushort* ksrc = kt + (size_t)b * 4096 * 32 + (size_t)kofs * 32 + (size_t)sr * 32 + sq * 8;
  const ushort* vsrc = vb + (size_t)b * 64 * 4096 + (size_t)sr * 4096 + kofs + sq * 16;
  int koff = sr * KP + sq * 8;
  int voff = sr * VP + sq * 16;

  {
    short8v kr = *reinterpret_cast<const short8v*>(ksrc);
    short8v v0 = *reinterpret_cast<const short8v*>(vsrc);
    short8v v1 = *reinterpret_cast<const short8v*>(vsrc + 8);
    *reinterpret_cast<short8v*>(&kls[0][koff]) = kr;
    *reinterpret_cast<short8v*>(&vls[0][voff]) = v0;
    *reinterpret_cast<short8v*>(&vls[0][voff + 8]) = v1;
  }

  ushort* plb = &pls[(w * 16 + lm) * VP];

  #pragma unroll 2
  for (int it = 0; it < NT; ++it) {
    int cur = it & 1;
    int nx = it < NT - 1 ? it + 1 : NT - 1;
    short8v knr = *reinterpret_cast<const short8v*>(ksrc + (size_t)nx * 2048);
    short8v vn0 = *reinterpret_cast<const short8v*>(vsrc + nx * 64);
    short8v vn1 = *reinterpret_cast<const short8v*>(vsrc + nx * 64 + 8);

    __syncthreads();

    const ushort* kb  = &kls[cur][0];
    const ushort* vbk = &vls[cur][0];

    f32x4 sf[4];
    #pragma unroll
    for (int nt = 0; nt < 4; ++nt) {
      short8v kf = *reinterpret_cast<const short8v*>(&kb[(nt * 16 + lm) * KP + lg * 8]);
      f32x4 z = {};
      sf[nt] = __builtin_amdgcn_mfma_f32_16x16x32_bf16(kf, qf, z, 0, 0, 0);
    }

    float tmax = -1e30f;
    #pragma unroll
    for (int nt = 0; nt < 4; ++nt)
      #pragma unroll
      for (int r = 0; r < 4; ++r) tmax = fmaxf(tmax, sf[nt][r]);
    tmax = fmaxf(tmax, __shfl_xor(tmax, 16));
    tmax = fmaxf(tmax, __shfl_xor(tmax, 32));
    if (!__all(tmax <= M)) {
      float Mn = fmaxf(M, tmax);
      float sc = __builtin_amdgcn_exp2f(M - Mn);
      M = Mn;
      S *= sc;
      #pragma unroll
      for (int ct = 0; ct < 4; ++ct)
        #pragma unroll
        for (int r = 0; r < 4; ++r) acc[ct][r] *= sc;
    }
    float tsum = 0.f;
    float p[16];
    #pragma unroll
    for (int nt = 0; nt < 4; ++nt)
      #pragma unroll
      for (int r = 0; r < 4; ++r) {
        float e = __builtin_amdgcn_exp2f(sf[nt][r] - M);
        p[nt * 4 + r] = e;
        tsum += e;
      }
    tsum += __shfl_xor(tsum, 16);
    tsum += __shfl_xor(tsum, 32);
    S += tsum;

    #pragma unroll
    for (int nt = 0; nt < 4; ++nt) {
      unsigned p01, p23;
      asm("v_cvt_pk_bf16_f32 %0, %1, %2" : "=v"(p01) : "v"(p[nt * 4 + 0]), "v"(p[nt * 4 + 1]));
      asm("v_cvt_pk_bf16_f32 %0, %1, %2" : "=v"(p23) : "v"(p[nt * 4 + 2]), "v"(p[nt * 4 + 3]));
      union { unsigned u[2]; short4v v; } pk;
      pk.u[0] = p01; pk.u[1] = p23;
      *reinterpret_cast<short4v*>(plb + nt * 16 + lg * 4) = pk.v;
    }
    asm volatile("s_waitcnt lgkmcnt(0)" ::: "memory");
    __builtin_amdgcn_sched_barrier(0);

    #pragma unroll
    for (int nh = 0; nh < 2; ++nh) {
      short8v pf = *reinterpret_cast<const short8v*>(plb + nh * 32 + lg * 8);
      #pragma unroll
      for (int ct = 0; ct < 4; ++ct) {
        short8v vf = *reinterpret_cast<const short8v*>(&vbk[(ct * 16 + lm) * VP + nh * 32 + lg * 8]);
        acc[ct] = __builtin_amdgcn_mfma_f32_16x16x32_bf16(vf, pf, acc[ct], 0, 0, 0);
      }
    }

    if (it < NT - 1) {
      *reinterpret_cast<short8v*>(&kls[cur ^ 1][koff]) = knr;
      *reinterpret_cast<short8v*>(&vls[cur ^ 1][voff]) = vn0;
      *reinterpret_cast<short8v*>(&vls[cur ^ 1][voff + 8]) = vn1;
    }
  }

  if (SPLIT) {
    int blk = (b * 64 + mt) * 4 + s;
    ushort* pa = pacc + (size_t)blk * 4096;
    #pragma unroll
    for (int ct = 0; ct < 4; ++ct)
      #pragma unroll
      for (int r = 0; r < 4; ++r)
        pa[(ct * 16 + lg * 4 + r) * 64 + w * 16 + lm] = f2bf(acc[ct][r]);
    if (l < 16) {
      pms[(size_t)blk * 128 + (w * 16 + lm) * 2]     = M;
      pms[(size_t)blk * 128 + (w * 16 + lm) * 2 + 1] = S;
    }
  } else {
    float inv = 1.f / S;
    #pragma unroll
    for (int ct = 0; ct < 4; ++ct)
      #pragma unroll
      for (int r = 0; r < 4; ++r)
        sa[(size_t)(b * 64 + ct * 16 + lg * 4 + r) * 4096 + m0 + w * 16 + lm] = acc[ct][r] * inv;
  }
}

// ---------------- channel gram partials: hi/lo bf16 MFMA, GN inline, 32 K-slices ----------------
__global__ __launch_bounds__(256) void gram_partial_k(const float* __restrict__ t0,
    const float* __restrict__ pt0, const float* __restrict__ gamma, const float* __restrict__ beta,
    float* __restrict__ pg) {
  __shared__ __align__(16) ushort hi[64 * 64];
  __shared__ __align__(16) ushort lo[64 * 64];
  int b = blockIdx.x >> 5, ks = blockIdx.x & 31;
  int tid = threadIdx.x;
  int wv = tid >> 6, l = tid & 63, lm = l & 15, lg = l >> 4;
  int wr = wv >> 1, wd = wv & 1;
  f32x4 acc[2][2] = {};
  int sr = tid >> 2, sq = tid & 3;
  int bg = b * 4 + (sr >> 4);
  float s0p = pt0[bg * 2], ss0p = pt0[bg * 2 + 1];
  float mq = s0p * (1.f / 65536.f);
  float rq = rsqrtf(ss0p * (1.f / 65536.f) - mq * mq + 1e-5f);
  float ga = rq * gamma[sr], bb2 = beta[sr] - mq * rq * gamma[sr];
  const float* xb = t0 + (size_t)b * 262144;

  for (int kt = 0; kt < 2; ++kt) {
    int n0 = ks * 128 + kt * 64;
    __syncthreads();
    const float* src = xb + (size_t)sr * 4096 + n0 + sq * 16;
    #pragma unroll
    for (int c2 = 0; c2 < 2; ++c2) {
      int chunk = sq * 2 + c2;
      int dchunk = chunk ^ (sr & 7);
      short8v hvv, lvv;
      #pragma unroll
      for (int j = 0; j < 8; ++j) {
        float v = fmaxf(fmaf(src[c2 * 8 + j], ga, bb2), 0.f);
        ushort hb = f2bf(v);
        union { float f; unsigned u; } uu; uu.u = ((unsigned)hb) << 16;
        hvv[j] = (short)hb;
        lvv[j] = (short)f2bf(v - uu.f);
      }
      *reinterpret_cast<short8v*>(&hi[sr * 64 + dchunk * 8]) = hvv;
      *reinterpret_cast<short8v*>(&lo[sr * 64 + dchunk * 8]) = lvv;
    }
    __syncthreads();
    #pragma unroll
    for (int kk = 0; kk < 2; ++kk) {
      short8v ah[2], al[2], bh[2], bl[2];
      #pragma unroll
      for (int i = 0; i < 2; ++i) {
        int rc = wr * 32 + i * 16 + lm;
        int ca = ((kk * 4 + lg) ^ (rc & 7)) * 8;
        ah[i] = *reinterpret_cast<const short8v*>(&hi[rc * 64 + ca]);
        al[i] = *reinterpret_cast<const short8v*>(&lo[rc * 64 + ca]);
        int rd = wd * 32 + i * 16 + lm;
        int cb = ((kk * 4 + lg) ^ (rd & 7)) * 8;
        bh[i] = *reinterpret_cast<const short8v*>(&hi[rd * 64 + cb]);
        bl[i] = *reinterpret_cast<const short8v*>(&lo[rd * 64 + cb]);
      }
      #pragma unroll
      for (int i = 0; i < 2; ++i)
        #pragma unroll
        for (int j = 0; j < 2; ++j) {
          acc[i][j] = __builtin_amdgcn_mfma_f32_16x16x32_bf16(ah[i], bh[j], acc[i][j], 0, 0, 0);
          acc[i][j] = __builtin_amdgcn_mfma_f32_16x16x32_bf16(ah[i], bl[j], acc[i][j], 0, 0, 0);
          acc[i][j] = __builtin_amdgcn_mfma_f32_16x16x32_bf16(al[i], bh[j], acc[i][j], 0, 0, 0);
        }
    }
  }
  float* pgb = pg + (size_t)blockIdx.x * 4096;
  #pragma unroll
  for (int i = 0; i < 2; ++i)
    #pragma unroll
    for (int j = 0; j < 2; ++j)
      #pragma unroll
      for (int r = 0; r < 4; ++r) {
        int c = wr * 32 + i * 16 + lg * 4 + r;
        int d = wd * 32 + j * 16 + lm;
        pgb[c * 64 + d] = acc[i][j][r];
      }
}

// ---------------- reduce partials + row softmax -> Ac[b][c][d] ----------------
__global__ __launch_bounds__(256) void gram_softmax_k(const float* __restrict__ pg, float* __restrict__ Ac) {
  int b = blockIdx.x;
  int t = threadIdx.x;
  int r = t >> 2, q = t & 3;
  float4 s[4] = {};
  for (int ks = 0; ks < 32; ++ks) {
    const float* row = pg + ((size_t)(b * 32 + ks) * 64 + r) * 64 + q * 16;
    #pragma unroll
    for (int i = 0; i < 4; ++i) {
      float4 v = *reinterpret_cast<const float4*>(row + i * 4);
      s[i].x += v.x; s[i].y += v.y; s[i].z += v.z; s[i].w += v.w;
    }
  }
  float mx = -1e30f;
  #pragma unroll
  for (int i = 0; i < 4; ++i)
    mx = fmaxf(mx, fmaxf(fmaxf(s[i].x, s[i].y), fmaxf(s[i].z, s[i].w)));
  mx = fmaxf(mx, __shfl_xor(mx, 1));
  mx = fmaxf(mx, __shfl_xor(mx, 2));
  float sum = 0.f;
  #pragma unroll
  for (int i = 0; i < 4; ++i) {
    s[i].x = __expf(s[i].x - mx); s[i].y = __expf(s[i].y - mx);
    s[i].z = __expf(s[i].z - mx); s[i].w = __expf(s[i].w - mx);
    sum += s[i].x + s[i].y + s[i].z + s[i].w;
  }
  sum += __shfl_xor(sum, 1);
  sum += __shfl_xor(sum, 2);
  float inv = 1.f / sum;
  float* dst = Ac + ((size_t)(b * 64 + r)) * 64 + q * 16;
  #pragma unroll
  for (int i = 0; i < 4; ++i) {
    float4 o; o.x = s[i].x * inv; o.y = s[i].y * inv; o.z = s[i].z * inv; o.w = s[i].w * inv;
    *reinterpret_cast<float4*>(dst + i * 4) = o;
  }
}

// ---------------- y = x1 + sa(+combine) + Ac @ x1 -> bf16 [b][n][ci]; GN inline ----------------
template<int NSPLIT>
__global__ __launch_bounds__(256) void ca_apply_k(const float* __restrict__ t0,
    const float* __restrict__ pt0, const float* __restrict__ gamma, const float* __restrict__ beta,
    const float* __restrict__ Ac, const float* __restrict__ sa,
    const ushort* __restrict__ pacc, const float* __restrict__ pms, ushort* __restrict__ yt) {
  __shared__ float x1f[64 * 72];
  __shared__ float acf[64 * 72];
  __shared__ float wls[4 * 64];
  int b = blockIdx.x >> 6, mt = blockIdx.x & 63;
  int n0 = mt * 64;
  int tid = threadIdx.x;
  {
    int d = tid >> 2, q = tid & 3;
    int bg = b * 4 + (d >> 4);
    float s0p = pt0[bg * 2], ss0p = pt0[bg * 2 + 1];
    float mq = s0p * (1.f / 65536.f);
    float rq = rsqrtf(ss0p * (1.f / 65536.f) - mq * mq + 1e-5f);
    float ga = rq * gamma[d], bb2 = beta[d] - mq * rq * gamma[d];
    const float* xs = t0 + (size_t)(b * 64 + d) * 4096 + n0 + q * 16;
    const float* as = Ac + (size_t)(b * 64 + d) * 64 + q * 16;
    #pragma unroll
    for (int i = 0; i < 4; ++i) {
      float4 v = *reinterpret_cast<const float4*>(xs + i * 4);
      x1f[d * 72 + q * 16 + i * 4 + 0] = fmaxf(fmaf(v.x, ga, bb2), 0.f);
      x1f[d * 72 + q * 16 + i * 4 + 1] = fmaxf(fmaf(v.y, ga, bb2), 0.f);
      x1f[d * 72 + q * 16 + i * 4 + 2] = fmaxf(fmaf(v.z, ga, bb2), 0.f);
      x1f[d * 72 + q * 16 + i * 4 + 3] = fmaxf(fmaf(v.w, ga, bb2), 0.f);
      float4 a = *reinterpret_cast<const float4*>(as + i * 4);
      acf[d * 72 + q * 16 + i * 4 + 0] = a.x;
      acf[d * 72 + q * 16 + i * 4 + 1] = a.y;
      acf[d * 72 + q * 16 + i * 4 + 2] = a.z;
      acf[d * 72 + q * 16 + i * 4 + 3] = a.w;
    }
  }
  if (NSPLIT > 1 && tid < 64) {
    int m = tid;
    size_t msb = (size_t)(b * 64 + mt) * NSPLIT * 128;
    float Ms[NSPLIT], Ss[NSPLIT];
    float Mg = -1e30f;
    #pragma unroll
    for (int s = 0; s < NSPLIT; ++s) {
      Ms[s] = pms[msb + s * 128 + m * 2];
      Ss[s] = pms[msb + s * 128 + m * 2 + 1];
      Mg = fmaxf(Mg, Ms[s]);
    }
    float Stot = 0.f;
    #pragma unroll
    for (int s = 0; s < NSPLIT; ++s) {
      float wv = __builtin_amdgcn_exp2f(Ms[s] - Mg);
      wls[s * 64 + m] = wv;
      Stot += wv * Ss[s];
    }
    float inv = 1.f / Stot;
    #pragma unroll
    for (int s = 0; s < NSPLIT; ++s) wls[s * 64 + m] *= inv;
  }
  __syncthreads();
  int m = tid & 63, cg = tid >> 6;
  float sval[16];
  if (NSPLIT > 1) {
    #pragma unroll
    for (int ci = 0; ci < 16; ++ci) sval[ci] = 0.f;
    const ushort* pb = pacc + (size_t)(b * 64 + mt) * NSPLIT * 4096;
    #pragma unroll
    for (int s = 0; s < NSPLIT; ++s) {
      float wv = wls[s * 64 + m];
      #pragma unroll
      for (int ci = 0; ci < 16; ++ci)
        sval[ci] = fmaf(wv, bf2f(pb[s * 4096 + (cg * 16 + ci) * 64 + m]), sval[ci]);
    }
  } else {
    #pragma unroll
    for (int ci = 0; ci < 16; ++ci)
      sval[ci] = sa[(size_t)(b * 64 + cg * 16 + ci) * 4096 + n0 + m];
  }
  float xcol[64];
  #pragma unroll
  for (int d = 0; d < 64; ++d) xcol[d] = x1f[d * 72 + m];
  union { ushort u[16]; short8v v[2]; } pk;
  #pragma unroll
  for (int ci = 0; ci < 16; ++ci) {
    int c = cg * 16 + ci;
    float o = xcol[c] + sval[ci];
    const float* ar = &acf[c * 72];
    #pragma unroll
    for (int d4 = 0; d4 < 16; ++d4) {
      float4 a4 = *reinterpret_cast<const float4*>(ar + d4 * 4);
      o = fmaf(a4.x, xcol[d4 * 4 + 0], o);
      o = fmaf(a4.y, xcol[d4 * 4 + 1], o);
      o = fmaf(a4.z, xcol[d4 * 4 + 2], o);
      o = fmaf(a4.w, xcol[d4 * 4 + 3], o);
    }
    pk.u[ci] = f2bf(o);
  }
  ushort* dst = yt + (size_t)(b * 4096 + n0 + m) * 64 + cg * 16;
  *reinterpret_cast<short8v*>(dst) = pk.v[0];
  *reinterpret_cast<short8v*>(dst + 8) = pk.v[1];
}

extern "C" void kernel_launch(void* const* d_in, const int* in_sizes, int n_in,
                              void* d_out, int out_size, void* d_ws, size_t ws_size,
                              hipStream_t stream) {
  const float* x       = (const float*)d_in[0];
  const float* w_i     = (const float*)d_in[1];
  const float* b_i     = (const float*)d_in[2];
  const float* gamma_i = (const float*)d_in[3];
  const float* beta_i  = (const float*)d_in[4];
  const float* w_q     = (const float*)d_in[5];
  const float* b_q     = (const float*)d_in[6];
  const float* w_k     = (const float*)d_in[7];
  const float* b_k     = (const float*)d_in[8];
  const float* w_v     = (const float*)d_in[9];
  const float* b_v     = (const float*)d_in[10];
  const float* w_o     = (const float*)d_in[11];
  const float* b_o     = (const float*)d_in[12];
  const float* gamma_o = (const float*)d_in[13];
  const float* beta_o  = (const float*)d_in[14];
  float* ws = (float*)d_ws;
  float* t0 = ws + OFF_T0;
  ushort* qt  = (ushort*)(ws + OFF_QT);
  ushort* kt  = (ushort*)(ws + OFF_KT);
  ushort* vbp = (ushort*)(ws + OFF_VB);
  float* yb = ws + OFF_SA;             // fallback sa
  float* pg = ws + OFF_QT;             // gram partials alias qt+kt (dead after flash)
  ushort* ytp = (ushort*)(ws + OFF_YT);
  ushort* xbp = (ushort*)(ws + OFF_XB);
  float* ac = ws + OFF_AC;
  ushort* wbi = (ushort*)(ws + OFF_WBI);
  ushort* wbo = (ushort*)(ws + OFF_WBO);
  float* pt0 = ws + OFF_PT;
  float* pt1 = pt0 + 32;
  ushort* pacc = (ushort*)(ws + OFF_PO);
  float* pms  = ws + OFF_MS;
  float* outp = (float*)d_out;
  bool split = ws_size >= WS_NEED;

  wcvt2_k<<<864, 256, 0, stream>>>(w_i, w_o, wbi, wbo);
  xcvt_k<<<256, 256, 0, stream>>>(x, xbp, pt0);

  conv_mfma_k<<<256, 256, 0, stream>>>(xbp, wbi, b_i, t0, pt0);

  proj_all_k<<<256, 256, 0, stream>>>(t0, pt0, gamma_i, beta_i,
                                      w_q, b_q, w_k, b_k, w_v, b_v, qt, kt, vbp);

  if (split)
    flash_mfma_k<true><<<1024, 256, 0, stream>>>(qt, kt, vbp, yb, pacc, pms);
  else
    flash_mfma_k<false><<<256, 256, 0, stream>>>(qt, kt, vbp, yb, pacc, pms);

  gram_partial_k<<<128, 256, 0, stream>>>(t0, pt0, gamma_i, beta_i, pg);
  gram_softmax_k<<<4, 256, 0, stream>>>(pg, ac);

  if (split)
    ca_apply_k<4><<<256, 256, 0, stream>>>(t0, pt0, gamma_i, beta_i, ac, yb, pacc, pms, ytp);
  else
    ca_apply_k<1><<<256, 256, 0, stream>>>(t0, pt0, gamma_i, beta_i, ac, yb, pacc, pms, ytp);

  conv_mfma_k<<<256, 256, 0, stream>>>(ytp, wbo, b_o, t0, pt1);
  gn_apply_k<<<4096, 256, 0, stream>>>(t0, pt1, gamma_o, beta_o, outp);
}